// Round 18
// baseline (1915.796 us; speedup 1.0000x reference)
//
#include <hip/hip_runtime.h>
#include <hip/hip_bf16.h>
#include <math.h>

#define N_  6000
#define F_  16
#define S_  64
#define D_  256
#define H_  8
#define KK_ 32
#define L_  2
#define DH_ 32
#define E_  (N_*KK_ + N_)   // 198000 edges
#define NF_ (N_*F_)         // 96000 token rows

typedef float f32x4 __attribute__((ext_vector_type(4)));
typedef float f32v4 __attribute__((ext_vector_type(4)));
typedef __bf16 bf16_t;
typedef bf16_t bf16x8 __attribute__((ext_vector_type(8)));

// ---------------- device helpers ----------------

__device__ __forceinline__ float geluf(float x) {
  return 0.5f * x * (1.0f + erff(x * 0.7071067811865476f));
}
__device__ __forceinline__ float sigmf(float x) {
  return 1.0f / (1.0f + expf(-x));
}
__device__ __forceinline__ float block_sum_256(float v, float* red) {
  int tid = threadIdx.x;
  red[tid] = v; __syncthreads();
  #pragma unroll
  for (int s = 128; s > 0; s >>= 1) {
    if (tid < s) red[tid] += red[tid + s];
    __syncthreads();
  }
  float r = red[0];
  __syncthreads();
  return r;
}
__device__ __forceinline__ unsigned fmap(float f) {
  unsigned u = __float_as_uint(f);
  return (u & 0x80000000u) ? ~u : (u | 0x80000000u);
}
__device__ __forceinline__ float funmap(unsigned u) {
  unsigned b = (u & 0x80000000u) ? (u ^ 0x80000000u) : ~u;
  return __uint_as_float(b);
}

// ---------------- weight prep / small utils ----------------
__global__ void transpose12_kernel(const float* s0, const float* s1, const float* s2,
                                   const float* s3, const float* s4, const float* s5,
                                   const float* s6, const float* s7, const float* s8,
                                   const float* s9, const float* s10, const float* s11,
                                   __hip_bfloat16* __restrict__ dst) {
  int m = blockIdx.y;
  const float* src;
  switch (m) {
    case 0: src = s0; break; case 1: src = s1; break; case 2: src = s2; break;
    case 3: src = s3; break; case 4: src = s4; break; case 5: src = s5; break;
    case 6: src = s6; break; case 7: src = s7; break; case 8: src = s8; break;
    case 9: src = s9; break; case 10: src = s10; break; default: src = s11; break;
  }
  int o = blockIdx.x, i = threadIdx.x;
  dst[(size_t)m * 65536 + o * 256 + i] = __float2bfloat16(src[(size_t)i * 256 + o]);
}
__global__ void transpose_pred_kernel(const float* __restrict__ src, __hip_bfloat16* __restrict__ dst) {
  int o = blockIdx.x, i = threadIdx.x;   // [256,512] -> [512,256]
  dst[(size_t)o * 256 + i] = __float2bfloat16(src[(size_t)i * 512 + o]);
}
__global__ void biascat_kernel(const float* __restrict__ bq, const float* __restrict__ bk,
                               const float* __restrict__ bv, float* __restrict__ dst) {
  int s = blockIdx.x, l = blockIdx.y, t = threadIdx.x;
  const float* p = (s == 0) ? bq : (s == 1) ? bk : bv;
  dst[l * 768 + s * 256 + t] = p[l * 256 + t];
}
__global__ void gatbias_kernel(const float* __restrict__ gb, float* __restrict__ b3) {
  int t = blockIdx.x * 256 + threadIdx.x;
  if (t < 768) b3[t] = (t < 256) ? gb[t] : 0.f;
}
__global__ void gruw_cvt_kernel(const float* __restrict__ Wih,
                                __hip_bfloat16* __restrict__ Wh) {
  size_t idx = (size_t)blockIdx.x * 256 + threadIdx.x;  // 786432
  Wh[idx] = __float2bfloat16(Wih[idx]);
}
__global__ void zero_f_kernel(float* __restrict__ p, int n) {
  int i = blockIdx.x * 256 + threadIdx.x;
  if (i < n) p[i] = 0.f;
}
__global__ void init_scalar_kernel(float* __restrict__ p, const float* __restrict__ s, int n) {
  int i = blockIdx.x * 256 + threadIdx.x;
  if (i < n) p[i] = s[0];
}

// ---------------- GRU: single-bf16 MFMA, XOR-swizzled LDS, fused gate epilogue ----
__global__ __launch_bounds__(256)
void gru_mfma_kernel(const float* __restrict__ x,
                     const __hip_bfloat16* __restrict__ Wh,
                     const float* __restrict__ bih, const float* __restrict__ bhh,
                     float* __restrict__ emb) {
  __shared__ __align__(16) __hip_bfloat16 Ash[64 * 32];
  __shared__ __align__(16) __hip_bfloat16 Bsh[384 * 32];
  int kb = blockIdx.x, rb = blockIdx.y, f = blockIdx.z;
  int tid = threadIdx.x;
  int lane = tid & 63, wid = tid >> 6;
  int wrow = (wid & 1) * 32, wcol = (wid >> 1) * 64;
  int q = lane >> 4, m16 = lane & 15;

  f32x4 aR[2][4], aZ[2][4], aN[2][4];
  #pragma unroll
  for (int i = 0; i < 2; i++)
    #pragma unroll
    for (int j = 0; j < 4; j++) {
      aR[i][j] = (f32x4){0.f,0.f,0.f,0.f};
      aZ[i][j] = (f32x4){0.f,0.f,0.f,0.f};
      aN[i][j] = (f32x4){0.f,0.f,0.f,0.f};
    }

  for (int k0 = 0; k0 < 64; k0 += 32) {
    {
      int r = tid >> 2, ch = tid & 3;
      int gn = rb * 64 + r;
      bool ok = gn < N_;
      const float* src = x + ((size_t)gn * F_ + f) * S_ + k0 + ch * 8;
      union { __hip_bfloat16 h[8]; uint4 u; } t8;
      #pragma unroll
      for (int v = 0; v < 2; v++) {
        f32v4 d = ok ? *reinterpret_cast<const f32v4*>(src + v * 4) : (f32v4){0.f,0.f,0.f,0.f};
        t8.h[v * 4 + 0] = __float2bfloat16(d.x);
        t8.h[v * 4 + 1] = __float2bfloat16(d.y);
        t8.h[v * 4 + 2] = __float2bfloat16(d.z);
        t8.h[v * 4 + 3] = __float2bfloat16(d.w);
      }
      *reinterpret_cast<uint4*>(&Ash[r * 32 + (ch ^ (r & 3)) * 8]) = t8.u;
    }
    #pragma unroll
    for (int i = 0; i < 6; i++) {
      int cid = tid + i * 256;
      int row = cid >> 2, ch = cid & 3;
      size_t roff = ((size_t)f * 768 + (row >> 7) * 256 + kb * 128 + (row & 127)) * S_ + k0 + ch * 8;
      uint4 v = *reinterpret_cast<const uint4*>(Wh + roff);
      *reinterpret_cast<uint4*>(&Bsh[row * 32 + (ch ^ (row & 3)) * 8]) = v;
    }
    __syncthreads();
    bf16x8 ah[2];
    #pragma unroll
    for (int mt = 0; mt < 2; mt++) {
      int ar = wrow + mt * 16 + m16;
      ah[mt] = *reinterpret_cast<const bf16x8*>(&Ash[ar * 32 + (q ^ (ar & 3)) * 8]);
    }
    #pragma unroll
    for (int g = 0; g < 3; g++) {
      bf16x8 bh[4];
      #pragma unroll
      for (int nt = 0; nt < 4; nt++) {
        int br = g * 128 + wcol + nt * 16 + m16;
        bh[nt] = *reinterpret_cast<const bf16x8*>(&Bsh[br * 32 + (q ^ (br & 3)) * 8]);
      }
      #pragma unroll
      for (int mt = 0; mt < 2; mt++)
        #pragma unroll
        for (int nt = 0; nt < 4; nt++) {
          f32x4 acc = (g == 0) ? aR[mt][nt] : (g == 1) ? aZ[mt][nt] : aN[mt][nt];
          acc = __builtin_amdgcn_mfma_f32_16x16x32_bf16(ah[mt], bh[nt], acc, 0, 0, 0);
          if (g == 0) aR[mt][nt] = acc; else if (g == 1) aZ[mt][nt] = acc; else aN[mt][nt] = acc;
        }
    }
    __syncthreads();
  }
  #pragma unroll
  for (int mt = 0; mt < 2; mt++)
    #pragma unroll
    for (int nt = 0; nt < 4; nt++) {
      int k = kb * 128 + wcol + nt * 16 + m16;
      float brc = bih[f * 768 + k]       + bhh[f * 768 + k];
      float bzc = bih[f * 768 + 256 + k] + bhh[f * 768 + 256 + k];
      float bni = bih[f * 768 + 512 + k];
      float bnh = bhh[f * 768 + 512 + k];
      #pragma unroll
      for (int r4 = 0; r4 < 4; r4++) {
        int gn = rb * 64 + wrow + mt * 16 + q * 4 + r4;
        if (gn < N_) {
          float rr = sigmf(aR[mt][nt][r4] + brc);
          float zz = sigmf(aZ[mt][nt][r4] + bzc);
          float nn = tanhf(aN[mt][nt][r4] + bni + rr * bnh);
          emb[((size_t)gn * F_ + f) * D_ + k] = (1.f - zz) * nn;
        }
      }
    }
}

// ---------------- fused qkv GEMM + LN + attention (2 nodes/block, 512 threads) ----------
// 8 waves x (6 n-tiles x 2 nodes); same LDS as round 17 (2 blocks/CU) but double the
// waves for latency hiding. Per-(node,n-tile) MFMA chain identical -> bit-identical.
#define BSTRIDE 40

__device__ __forceinline__ void qkv_epilogue(f32x4 (&acc)[6], float (*tile)[772],
    const float* __restrict__ bias, __hip_bfloat16* __restrict__ out, int node,
    const float* __restrict__ gq, const float* __restrict__ bq,
    const float* __restrict__ gk, const float* __restrict__ bk,
    const float* __restrict__ gv, const float* __restrict__ bv,
    int tid, int lane, int w, int q, int m16) {
  __syncthreads();   // prior readers of this LDS region are done
  #pragma unroll
  for (int j = 0; j < 6; j++) {
    int col = (w * 6 + j) * 16 + m16;
    float bc = bias[col];
    #pragma unroll
    for (int r = 0; r < 4; r++)
      tile[q * 4 + r][col] = acc[j][r] + bc;
  }
  __syncthreads();

  // LN: 48 (row,slice) pairs, 6 per wave
  for (int ii = 0; ii < 6; ii++) {
    int sl = w * 6 + ii;
    int s = sl >> 4, f = sl & 15;
    float* p = &tile[f][s * 256];
    float4 d = *reinterpret_cast<float4*>(p + lane * 4);
    float sum = d.x + d.y + d.z + d.w;
    #pragma unroll
    for (int m = 1; m < 64; m <<= 1) sum += __shfl_xor(sum, m, 64);
    float mean = sum * (1.f / 256.f);
    float e0 = d.x - mean, e1 = d.y - mean, e2 = d.z - mean, e3 = d.w - mean;
    float sq = e0 * e0 + e1 * e1 + e2 * e2 + e3 * e3;
    #pragma unroll
    for (int m = 1; m < 64; m <<= 1) sq += __shfl_xor(sq, m, 64);
    float inv = rsqrtf(sq * (1.f / 256.f) + 1e-5f);
    const float* g  = (s == 0) ? gq : (s == 1) ? gk : gv;
    const float* bb = (s == 0) ? bq : (s == 1) ? bk : bv;
    float4 gg = *reinterpret_cast<const float4*>(g + lane * 4);
    float4 bo = *reinterpret_cast<const float4*>(bb + lane * 4);
    d.x = e0 * inv * gg.x + bo.x;
    d.y = e1 * inv * gg.y + bo.y;
    d.z = e2 * inv * gg.z + bo.z;
    d.w = e3 * inv * gg.w + bo.w;
    *reinterpret_cast<float4*>(p + lane * 4) = d;
  }
  __syncthreads();

  // attention: c = query token, h = head, qtr = d-range quarter (8 dims each)
  int c = tid & 15, h = (tid >> 4) & 7, qtr = tid >> 7;
  const float scale = 0.17677669529663687f;  // 1/sqrt(32)
  float sc[16];
  float mx = -3e38f;
  #pragma unroll
  for (int s = 0; s < 16; s++) {
    float a2 = 0.f;
    #pragma unroll
    for (int e = 0; e < 32; e++)
      a2 += tile[c][h * 32 + e] * tile[s][256 + h * 32 + e];
    sc[s] = a2 * scale;
    mx = fmaxf(mx, sc[s]);
  }
  float sum = 0.f;
  #pragma unroll
  for (int s = 0; s < 16; s++) { sc[s] = expf(sc[s] - mx); sum += sc[s]; }
  float inv = 1.f / sum;
  #pragma unroll
  for (int dd = 0; dd < 8; dd++) {
    int d = qtr * 8 + dd;
    float a2 = 0.f;
    #pragma unroll
    for (int s = 0; s < 16; s++) a2 += sc[s] * tile[s][512 + h * 32 + d];
    out[((size_t)node * 16 + c) * 256 + h * 32 + d] = __float2bfloat16(a2 * inv);
  }
}

__global__ __launch_bounds__(512, 2)
void qkv_attn2_kernel(const float* __restrict__ emb, const __hip_bfloat16* __restrict__ Wt,
                      const float* __restrict__ bias, __hip_bfloat16* __restrict__ out,
                      const float* __restrict__ gq, const float* __restrict__ bq,
                      const float* __restrict__ gk, const float* __restrict__ bk,
                      const float* __restrict__ gv, const float* __restrict__ bv) {
  __shared__ __align__(16) __hip_bfloat16 As[32 * 256];            // 16 KB
  __shared__ __align__(16) unsigned char shbuf[768 * BSTRIDE * 2]; // 61.4 KB: Bs / tile
  __hip_bfloat16* Bs = reinterpret_cast<__hip_bfloat16*>(shbuf);
  float (*tile)[772] = reinterpret_cast<float (*)[772]>(shbuf);    // 49.4 KB view
  int n0 = blockIdx.x * 2, tid = threadIdx.x;
  int lane = tid & 63, w = tid >> 6;       // 8 waves
  int q = lane >> 4, m16 = lane & 15;

  // stage A: 32 rows x 256 cols (fp32 -> bf16), swizzle ch^(r&7); 2 chunks/thread
  #pragma unroll
  for (int i = 0; i < 2; i++) {
    int cid = tid + i * 512;           // 0..1023
    int r = cid >> 5, ch = cid & 31;
    const float* src = emb + ((size_t)n0 * 16 + r) * 256 + ch * 8;
    union { __hip_bfloat16 h[8]; uint4 u; } t8;
    #pragma unroll
    for (int v = 0; v < 2; v++) {
      f32v4 d = *reinterpret_cast<const f32v4*>(src + v * 4);
      t8.h[v * 4 + 0] = __float2bfloat16(d.x);
      t8.h[v * 4 + 1] = __float2bfloat16(d.y);
      t8.h[v * 4 + 2] = __float2bfloat16(d.z);
      t8.h[v * 4 + 3] = __float2bfloat16(d.w);
    }
    *reinterpret_cast<uint4*>(&As[r * 256 + (ch ^ (r & 7)) * 8]) = t8.u;
  }

  // GEMM: wave w owns n-tiles w*6..w*6+5 for both nodes; K=256 in 8 k-slices
  f32x4 acc0[6], acc1[6];
  #pragma unroll
  for (int j = 0; j < 6; j++) {
    acc0[j] = (f32x4){0.f,0.f,0.f,0.f};
    acc1[j] = (f32x4){0.f,0.f,0.f,0.f};
  }
  for (int k = 0; k < 8; k++) {
    __syncthreads();   // protect Bs from previous iteration's readers
    // stage B k-slice: 768 rows x 32 cols, stride-40 rows; 6 chunk-stores/thread
    #pragma unroll
    for (int i = 0; i < 6; i++) {
      int cid = tid + i * 512;
      int row = cid >> 2, ch = cid & 3;
      uint4 v = *reinterpret_cast<const uint4*>(Wt + (size_t)row * 256 + k * 32 + ch * 8);
      *reinterpret_cast<uint4*>(&Bs[row * BSTRIDE + ch * 8]) = v;
    }
    __syncthreads();
    int c = k * 4 + q;
    bf16x8 a0 = *reinterpret_cast<const bf16x8*>(&As[m16 * 256 + (c ^ (m16 & 7)) * 8]);
    bf16x8 a1 = *reinterpret_cast<const bf16x8*>(&As[(16 + m16) * 256 + (c ^ (m16 & 7)) * 8]);
    #pragma unroll
    for (int j = 0; j < 6; j++) {
      int br = (w * 6 + j) * 16 + m16;
      bf16x8 b = *reinterpret_cast<const bf16x8*>(&Bs[br * BSTRIDE + q * 8]);
      acc0[j] = __builtin_amdgcn_mfma_f32_16x16x32_bf16(a0, b, acc0[j], 0, 0, 0);
      acc1[j] = __builtin_amdgcn_mfma_f32_16x16x32_bf16(a1, b, acc1[j], 0, 0, 0);
    }
  }

  // per-node epilogues (constant indexing after inlining)
  qkv_epilogue(acc0, tile, bias, out, n0,     gq, bq, gk, bk, gv, bv, tid, lane, w, q, m16);
  qkv_epilogue(acc1, tile, bias, out, n0 + 1, gq, bq, gk, bk, gv, bv, tid, lane, w, q, m16);
}

// ---------------- MFMA GEMM: A fp32 (cvt), B pre-bf16 [Nt,K] ----------------
template <int EPI>
__global__ __launch_bounds__(256)
void gemm_fA_bB(const float* __restrict__ A, const __hip_bfloat16* __restrict__ Btb,
                const float* __restrict__ bias, float* __restrict__ C,
                int M, int K, int Nt) {
  __shared__ __align__(16) __hip_bfloat16 As[128 * 32];
  __shared__ __align__(16) __hip_bfloat16 Bs[128 * 32];
  int mb = blockIdx.y * 128, nb = blockIdx.x * 128;
  int tid = threadIdx.x;
  int lane = tid & 63, wid = tid >> 6;
  int wm = (wid >> 1) * 64, wn = (wid & 1) * 64;
  int q = lane >> 4, m16 = lane & 15;
  int arow = tid >> 1;
  int acol = (tid & 1) * 16;

  f32x4 acc[4][4];
  #pragma unroll
  for (int i = 0; i < 4; i++)
    #pragma unroll
    for (int j = 0; j < 4; j++) acc[i][j] = (f32x4){0.f, 0.f, 0.f, 0.f};

  uint4 z4 = {0u,0u,0u,0u};
  for (int k0 = 0; k0 < K; k0 += 32) {
    {
      bool ok = (mb + arow) < M;
      const float* src = A + (size_t)(mb + arow) * K + k0 + acol;
      union { __hip_bfloat16 h[16]; uint4 u[2]; } tmp;
      #pragma unroll
      for (int v = 0; v < 4; v++) {
        f32v4 d = ok ? *reinterpret_cast<const f32v4*>(src + v * 4) : (f32v4){0.f,0.f,0.f,0.f};
        tmp.h[v * 4 + 0] = __float2bfloat16(d.x);
        tmp.h[v * 4 + 1] = __float2bfloat16(d.y);
        tmp.h[v * 4 + 2] = __float2bfloat16(d.z);
        tmp.h[v * 4 + 3] = __float2bfloat16(d.w);
      }
      uint4* dst = reinterpret_cast<uint4*>(&As[arow * 32 + acol]);
      dst[0] = tmp.u[0]; dst[1] = tmp.u[1];
    }
    {
      bool ok = (nb + arow) < Nt;
      const uint4* src = reinterpret_cast<const uint4*>(Btb + (size_t)(nb + arow) * K + k0 + acol);
      uint4* dst = reinterpret_cast<uint4*>(&Bs[arow * 32 + acol]);
      dst[0] = ok ? src[0] : z4; dst[1] = ok ? src[1] : z4;
    }
    __syncthreads();
    bf16x8 av[4], bv[4];
    #pragma unroll
    for (int mt = 0; mt < 4; mt++)
      av[mt] = *reinterpret_cast<const bf16x8*>(&As[(wm + mt * 16 + m16) * 32 + q * 8]);
    #pragma unroll
    for (int nt = 0; nt < 4; nt++)
      bv[nt] = *reinterpret_cast<const bf16x8*>(&Bs[(wn + nt * 16 + m16) * 32 + q * 8]);
    #pragma unroll
    for (int mt = 0; mt < 4; mt++)
      #pragma unroll
      for (int nt = 0; nt < 4; nt++)
        acc[mt][nt] = __builtin_amdgcn_mfma_f32_16x16x32_bf16(av[mt], bv[nt], acc[mt][nt], 0, 0, 0);
    __syncthreads();
  }
  #pragma unroll
  for (int mt = 0; mt < 4; mt++) {
    #pragma unroll
    for (int nt = 0; nt < 4; nt++) {
      #pragma unroll
      for (int r = 0; r < 4; r++) {
        int row = mb + wm + mt * 16 + q * 4 + r;
        int col = nb + wn + nt * 16 + m16;
        if (row < M && col < Nt) {
          float c = acc[mt][nt][r] + (bias ? bias[col] : 0.f);
          if (EPI == 1) c = geluf(c);
          C[(size_t)row * Nt + col] = c;
        }
      }
    }
  }
}

// ---- GEMM + fused gelu-dot epilogue (A fp32, B pre-bf16) ----
__global__ __launch_bounds__(256)
void gemm_dot2(const float* __restrict__ A, const __hip_bfloat16* __restrict__ Btb,
               const float* __restrict__ bias, const float* __restrict__ w2,
               float* __restrict__ out1, int M, int K, int Nt) {
  __shared__ __align__(16) __hip_bfloat16 As[128 * 32];
  __shared__ __align__(16) __hip_bfloat16 Bs[128 * 32];
  int mb = blockIdx.y * 128, nb = blockIdx.x * 128;
  int tid = threadIdx.x;
  int lane = tid & 63, wid = tid >> 6;
  int wm = (wid >> 1) * 64, wn = (wid & 1) * 64;
  int q = lane >> 4, m16 = lane & 15;
  int arow = tid >> 1;
  int acol = (tid & 1) * 16;

  f32x4 acc[4][4];
  #pragma unroll
  for (int i = 0; i < 4; i++)
    #pragma unroll
    for (int j = 0; j < 4; j++) acc[i][j] = (f32x4){0.f, 0.f, 0.f, 0.f};

  uint4 z4 = {0u,0u,0u,0u};
  for (int k0 = 0; k0 < K; k0 += 32) {
    {
      bool ok = (mb + arow) < M;
      const float* src = A + (size_t)(mb + arow) * K + k0 + acol;
      union { __hip_bfloat16 h[16]; uint4 u[2]; } tmp;
      #pragma unroll
      for (int v = 0; v < 4; v++) {
        f32v4 d = ok ? *reinterpret_cast<const f32v4*>(src + v * 4) : (f32v4){0.f,0.f,0.f,0.f};
        tmp.h[v * 4 + 0] = __float2bfloat16(d.x);
        tmp.h[v * 4 + 1] = __float2bfloat16(d.y);
        tmp.h[v * 4 + 2] = __float2bfloat16(d.z);
        tmp.h[v * 4 + 3] = __float2bfloat16(d.w);
      }
      uint4* dst = reinterpret_cast<uint4*>(&As[arow * 32 + acol]);
      dst[0] = tmp.u[0]; dst[1] = tmp.u[1];
    }
    {
      bool ok = (nb + arow) < Nt;
      const uint4* src = reinterpret_cast<const uint4*>(Btb + (size_t)(nb + arow) * K + k0 + acol);
      uint4* dst = reinterpret_cast<uint4*>(&Bs[arow * 32 + acol]);
      dst[0] = ok ? src[0] : z4; dst[1] = ok ? src[1] : z4;
    }
    __syncthreads();
    bf16x8 av[4], bv[4];
    #pragma unroll
    for (int mt = 0; mt < 4; mt++)
      av[mt] = *reinterpret_cast<const bf16x8*>(&As[(wm + mt * 16 + m16) * 32 + q * 8]);
    #pragma unroll
    for (int nt = 0; nt < 4; nt++)
      bv[nt] = *reinterpret_cast<const bf16x8*>(&Bs[(wn + nt * 16 + m16) * 32 + q * 8]);
    #pragma unroll
    for (int mt = 0; mt < 4; mt++)
      #pragma unroll
      for (int nt = 0; nt < 4; nt++)
        acc[mt][nt] = __builtin_amdgcn_mfma_f32_16x16x32_bf16(av[mt], bv[nt], acc[mt][nt], 0, 0, 0);
    __syncthreads();
  }
  #pragma unroll
  for (int mt = 0; mt < 4; mt++) {
    #pragma unroll
    for (int r = 0; r < 4; r++) {
      int row = mb + wm + mt * 16 + q * 4 + r;
      float s = 0.f;
      #pragma unroll
      for (int nt = 0; nt < 4; nt++) {
        int col = nb + wn + nt * 16 + m16;
        float c = geluf(acc[mt][nt][r] + bias[col]);
        s += c * w2[col];
      }
      #pragma unroll
      for (int m = 1; m < 16; m <<= 1) s += __shfl_xor(s, m, 64);
      if (m16 == 0 && row < M) atomicAdd(&out1[row], s);
    }
  }
}

// ---- fused Wo GEMM + gelu residual + LN: emb = LN(gelu(obuf@Wo^T + bo) + emb) ----
__global__ __launch_bounds__(256)
void wo_resid_ln_kernel(const __hip_bfloat16* __restrict__ A, const __hip_bfloat16* __restrict__ Btb,
                        const float* __restrict__ bias, float* __restrict__ emb,
                        const float* __restrict__ g, const float* __restrict__ b, int M) {
  __shared__ __align__(16) __hip_bfloat16 As[64 * 32];
  __shared__ __align__(16) __hip_bfloat16 Bs[256 * 32];
  int mb = blockIdx.x * 64;
  int tid = threadIdx.x, lane = tid & 63, w = tid >> 6;
  int q = lane >> 4, m16 = lane & 15;
  f32x4 acc[16];
  #pragma unroll
  for (int nt = 0; nt < 16; nt++) acc[nt] = (f32x4){0.f,0.f,0.f,0.f};
  uint4 z4 = {0u,0u,0u,0u};
  for (int k0 = 0; k0 < 256; k0 += 32) {
    { int r = tid >> 2, c0 = (tid & 3) * 8;
      int gr = mb + r;
      uint4 v = (gr < M) ? *reinterpret_cast<const uint4*>(A + (size_t)gr * 256 + k0 + c0) : z4;
      *reinterpret_cast<uint4*>(&As[r * 32 + c0]) = v; }
    { const uint4* src = reinterpret_cast<const uint4*>(Btb + (size_t)tid * 256 + k0);
      uint4* dst = reinterpret_cast<uint4*>(&Bs[tid * 32]);
      dst[0] = src[0]; dst[1] = src[1]; dst[2] = src[2]; dst[3] = src[3]; }
    __syncthreads();
    bf16x8 av = *reinterpret_cast<const bf16x8*>(&As[(w * 16 + m16) * 32 + q * 8]);
    #pragma unroll
    for (int nt = 0; nt < 16; nt++) {
      bf16x8 bv = *reinterpret_cast<const bf16x8*>(&Bs[(nt * 16 + m16) * 32 + q * 8]);
      acc[nt] = __builtin_amdgcn_mfma_f32_16x16x32_bf16(av, bv, acc[nt], 0, 0, 0);
    }
    __syncthreads();
  }
  #pragma unroll
  for (int r = 0; r < 4; r++) {
    int grow = mb + w * 16 + q * 4 + r;
    if (grow >= M) continue;     // uniform within each 16-lane group
    float s = 0.f;
    #pragma unroll
    for (int nt = 0; nt < 16; nt++) {
      int col = nt * 16 + m16;
      float v = geluf(acc[nt][r] + bias[col]) + emb[(size_t)grow * 256 + col];
      acc[nt][r] = v; s += v;
    }
    #pragma unroll
    for (int m = 1; m < 16; m <<= 1) s += __shfl_xor(s, m, 64);
    float mean = s * (1.f / 256.f);
    float sq = 0.f;
    #pragma unroll
    for (int nt = 0; nt < 16; nt++) { float d = acc[nt][r] - mean; sq += d * d; }
    #pragma unroll
    for (int m = 1; m < 16; m <<= 1) sq += __shfl_xor(sq, m, 64);
    float inv = rsqrtf(sq * (1.f / 256.f) + 1e-5f);
    #pragma unroll
    for (int nt = 0; nt < 16; nt++) {
      int col = nt * 16 + m16;
      emb[(size_t)grow * 256 + col] = (acc[nt][r] - mean) * inv * g[col] + b[col];
    }
  }
}

// ---------------- split-bf16 sim GEMM ----------------
__global__ __launch_bounds__(256)
void sim_split_kernel(const __hip_bfloat16* __restrict__ xh, const __hip_bfloat16* __restrict__ xl,
                      float* __restrict__ C) {
  __shared__ __align__(16) __hip_bfloat16 Ah[128 * 32];
  __shared__ __align__(16) __hip_bfloat16 Al[128 * 32];
  __shared__ __align__(16) __hip_bfloat16 Bh[128 * 32];
  __shared__ __align__(16) __hip_bfloat16 Bl[128 * 32];
  int mb = blockIdx.y * 128, nb = blockIdx.x * 128;
  int tid = threadIdx.x;
  int lane = tid & 63, wid = tid >> 6;
  int wm = (wid >> 1) * 64, wn = (wid & 1) * 64;
  int q = lane >> 4, m16 = lane & 15;
  int row = tid >> 1, halfk = (tid & 1) * 16;

  f32x4 acc[4][4];
  #pragma unroll
  for (int i = 0; i < 4; i++)
    #pragma unroll
    for (int j = 0; j < 4; j++) acc[i][j] = (f32x4){0.f, 0.f, 0.f, 0.f};

  uint4 z = {0u, 0u, 0u, 0u};
  for (int k0 = 0; k0 < 256; k0 += 32) {
    {
      int gr = mb + row; bool ok = gr < N_;
      const uint4* sh = reinterpret_cast<const uint4*>(xh + (size_t)gr * 256 + k0 + halfk);
      const uint4* sl = reinterpret_cast<const uint4*>(xl + (size_t)gr * 256 + k0 + halfk);
      uint4* dh = reinterpret_cast<uint4*>(&Ah[row * 32 + halfk]);
      uint4* dl = reinterpret_cast<uint4*>(&Al[row * 32 + halfk]);
      dh[0] = ok ? sh[0] : z; dh[1] = ok ? sh[1] : z;
      dl[0] = ok ? sl[0] : z; dl[1] = ok ? sl[1] : z;
    }
    {
      int gc = nb + row; bool ok = gc < N_;
      const uint4* sh = reinterpret_cast<const uint4*>(xh + (size_t)gc * 256 + k0 + halfk);
      const uint4* sl = reinterpret_cast<const uint4*>(xl + (size_t)gc * 256 + k0 + halfk);
      uint4* dh = reinterpret_cast<uint4*>(&Bh[row * 32 + halfk]);
      uint4* dl = reinterpret_cast<uint4*>(&Bl[row * 32 + halfk]);
      dh[0] = ok ? sh[0] : z; dh[1] = ok ? sh[1] : z;
      dl[0] = ok ? sl[0] : z; dl[1] = ok ? sl[1] : z;
    }
    __syncthreads();
    bf16x8 avh[4], avl[4], bvh[4], bvl[4];
    #pragma unroll
    for (int mt = 0; mt < 4; mt++) {
      avh[mt] = *reinterpret_cast<const bf16x8*>(&Ah[(wm + mt * 16 + m16) * 32 + q * 8]);
      avl[mt] = *reinterpret_cast<const bf16x8*>(&Al[(wm + mt * 16 + m16) * 32 + q * 8]);
    }
    #pragma unroll
    for (int nt = 0; nt < 4; nt++) {
      bvh[nt] = *reinterpret_cast<const bf16x8*>(&Bh[(wn + nt * 16 + m16) * 32 + q * 8]);
      bvl[nt] = *reinterpret_cast<const bf16x8*>(&Bl[(wn + nt * 16 + m16) * 32 + q * 8]);
    }
    #pragma unroll
    for (int mt = 0; mt < 4; mt++)
      #pragma unroll
      for (int nt = 0; nt < 4; nt++) {
        acc[mt][nt] = __builtin_amdgcn_mfma_f32_16x16x32_bf16(avh[mt], bvh[nt], acc[mt][nt], 0, 0, 0);
        acc[mt][nt] = __builtin_amdgcn_mfma_f32_16x16x32_bf16(avh[mt], bvl[nt], acc[mt][nt], 0, 0, 0);
        acc[mt][nt] = __builtin_amdgcn_mfma_f32_16x16x32_bf16(avl[mt], bvh[nt], acc[mt][nt], 0, 0, 0);
      }
    __syncthreads();
  }
  #pragma unroll
  for (int mt = 0; mt < 4; mt++)
    #pragma unroll
    for (int nt = 0; nt < 4; nt++)
      #pragma unroll
      for (int r = 0; r < 4; r++) {
        int rr = mb + wm + mt * 16 + q * 4 + r;
        int cc = nb + wn + nt * 16 + m16;
        if (rr < N_ && cc < N_) C[(size_t)rr * N_ + cc] = acc[mt][nt][r];
      }
}

// ---------------- fused fi-softmax + node pooling + l2norm/split ----------------
__global__ __launch_bounds__(256)
void node_prep_kernel(const float* __restrict__ wbuf, const float* __restrict__ emb,
                      float* __restrict__ node, __hip_bfloat16* __restrict__ xh,
                      __hip_bfloat16* __restrict__ xl) {
  __shared__ float wsh[16];
  __shared__ float red[256];
  int n = blockIdx.x, tid = threadIdx.x;
  if (tid < 16) wsh[tid] = wbuf[n * 16 + tid];
  __syncthreads();
  float mx = -3e38f;
  #pragma unroll
  for (int f = 0; f < 16; f++) mx = fmaxf(mx, wsh[f]);
  float e[16], ssum = 0.f;
  #pragma unroll
  for (int f = 0; f < 16; f++) { e[f] = expf(wsh[f] - mx); ssum += e[f]; }
  float inv = 1.f / ssum;
  float acc = 0.f;
  #pragma unroll
  for (int f = 0; f < 16; f++)
    acc += e[f] * emb[((size_t)n * 16 + f) * 256 + tid];
  acc *= inv;
  node[(size_t)n * 256 + tid] = acc;
  float ss = block_sum_256(acc * acc, red);
  float y = acc * rsqrtf(ss + 1e-12f);
  __hip_bfloat16 h = __float2bfloat16(y);
  xh[(size_t)n * 256 + tid] = h;
  xl[(size_t)n * 256 + tid] = __float2bfloat16(y - __bfloat162float(h));
}

// ---------------- top-k / bottom-k: early-exit dual-pass bitwise binary search ----------------
__global__ __launch_bounds__(256)
void topk_kernel(const float* __restrict__ sim, int* __restrict__ top,
                 int* __restrict__ bot) {
  __shared__ unsigned wsum[2][4];
  __shared__ unsigned short tie[1024];
  __shared__ unsigned s_out, s_tcnt;
  int i = blockIdx.x, tid = threadIdx.x;
  int lane = tid & 63, wid = tid >> 6;
  unsigned raw[24];
  unsigned validmask = 0;
  #pragma unroll
  for (int k = 0; k < 24; k++) {
    int j = tid + k * 256;
    bool ok = (j < N_) && (j != i);
    raw[k] = ok ? fmap(sim[(size_t)i * N_ + j]) : 0u;
    validmask |= (ok ? 1u : 0u) << k;
  }
  unsigned match_t = validmask, match_b = validmask;
  unsigned sel_t = 0, sel_b = 0;
  unsigned r_t = KK_, r_b = KK_;
  bool act_t = true, act_b = true;
  for (int bit = 31; bit >= 0; bit--) {
    unsigned bmask = 0;
    #pragma unroll
    for (int k = 0; k < 24; k++) bmask |= ((raw[k] >> bit) & 1u) << k;
    unsigned effb = (~bmask) & 0x00ffffffu;
    unsigned packed = (unsigned)__popc(match_t & bmask) |
                      ((unsigned)__popc(match_b & effb) << 16);
    #pragma unroll
    for (int m = 1; m < 64; m <<= 1) packed += (unsigned)__shfl_xor((int)packed, m, 64);
    if (lane == 0) wsum[bit & 1][wid] = packed;
    __syncthreads();
    unsigned tot = wsum[bit & 1][0] + wsum[bit & 1][1] + wsum[bit & 1][2] + wsum[bit & 1][3];
    unsigned tt = tot & 0xffffu, tb = tot >> 16;
    if (act_t) {
      if (tt >= r_t) {
        match_t &= bmask;
        if (tt == r_t) { sel_t |= match_t; act_t = false; }
      } else { sel_t |= match_t & bmask; r_t -= tt; match_t &= ~bmask; }
    }
    if (act_b) {
      if (tb >= r_b) {
        match_b &= effb;
        if (tb == r_b) { sel_b |= match_b; act_b = false; }
      } else { sel_b |= match_b & effb; r_b -= tb; match_b &= ~effb; }
    }
    if (!(act_t || act_b)) break;
  }
  for (int pass = 0; pass < 2; pass++) {
    int* dst = pass ? bot : top;
    unsigned sel = pass ? sel_b : sel_t;
    unsigned match = pass ? match_b : match_t;
    bool act = pass ? act_b : act_t;        // block-uniform
    unsigned r = pass ? r_b : r_t;
    if (tid == 0) { s_out = 0; s_tcnt = 0; }
    __syncthreads();
    unsigned s = sel;
    while (s) {
      int k = __ffs(s) - 1; s &= s - 1;
      unsigned p = atomicAdd(&s_out, 1u);
      dst[i * KK_ + p] = tid + k * 256;
    }
    if (act) {
      unsigned m0 = match;
      while (m0) {
        int k = __ffs(m0) - 1; m0 &= m0 - 1;
        unsigned qx = atomicAdd(&s_tcnt, 1u);
        if (qx < 1024u) tie[qx] = (unsigned short)(tid + k * 256);
      }
    }
    __syncthreads();
    if (act) {   // rare exact-tie path: take r lowest indices
      int tcnt = (int)min(s_tcnt, 1024u);
      int basep = KK_ - (int)r;
      int last = -1;
      for (int t = 0; t < (int)r; t++) {
        unsigned best = 0xffffffffu;
        for (int idx = tid; idx < tcnt; idx += 256) {
          int j = (int)tie[idx];
          if (j > last && (unsigned)j < best) best = (unsigned)j;
        }
        #pragma unroll
        for (int m = 1; m < 64; m <<= 1) best = min(best, (unsigned)__shfl_xor((int)best, m, 64));
        if (lane == 0) wsum[t & 1][wid] = best;
        __syncthreads();
        best = min(min(wsum[t & 1][0], wsum[t & 1][1]), min(wsum[t & 1][2], wsum[t & 1][3]));
        last = (int)best;
        if (tid == 0) dst[i * KK_ + basep + t] = last;
        __syncthreads();
      }
    }
    __syncthreads();
  }
}

// ---------------- GAT (both graphs per dispatch) ----------------
__device__ __forceinline__ void edge_decode(int e, const int* nbr, int& src, int& tgt, bool& valid) {
  if (e < N_ * KK_) { src = e >> 5; tgt = nbr[e]; valid = (src != tgt); }
  else { src = tgt = e - N_ * KK_; valid = true; }
}

__global__ void gat_esed2_kernel(const float* __restrict__ gout, const float* __restrict__ asrc,
                                 const float* __restrict__ adst,
                                 float* __restrict__ es, float* __restrict__ ed) {
  int idx = blockIdx.x * 256 + threadIdx.x;
  if (idx >= 2 * N_ * H_) return;
  int g = idx / (N_ * H_), r = idx - g * (N_ * H_);
  int hh = r & 7, node = r >> 3;
  const float* hp = gout + 256 + 256 * g + (size_t)node * 768 + hh * 32;
  const float* as = asrc + 256 + 256 * g + hh * 32;
  const float* ad = adst + 256 + 256 * g + hh * 32;
  float a = 0.f, b = 0.f;
  for (int d = 0; d < 32; d++) { float hv = hp[d]; a += hv * as[d]; b += hv * ad[d]; }
  es[idx] = a; ed[idx] = b;
}

__global__ void gat_init2_kernel(unsigned* __restrict__ mu, float* __restrict__ sb,
                                 float* __restrict__ tobo) {
  int idx = blockIdx.x * 256 + threadIdx.x;
  if (idx < 2 * N_ * H_) { mu[idx] = fmap(-1e9f); sb[idx] = 0.f; }
  if (idx < 2 * N_ * D_) tobo[idx] = 0.f;
}

__global__ void gat_edge_max2_kernel(const int* __restrict__ topi, const int* __restrict__ boti,
                                     const float* __restrict__ es, const float* __restrict__ ed,
                                     unsigned* __restrict__ mu) {
  int t = blockIdx.x * 256 + threadIdx.x;
  if (t >= 2 * E_ * H_) return;
  int g = t / (E_ * H_), r = t - g * (E_ * H_);
  int e = r >> 3, hh = r & 7;
  const int* nbr = g ? boti : topi;
  int src, tgt; bool valid;
  edge_decode(e, nbr, src, tgt, valid);
  float ev = -1e9f;
  if (valid) {
    float xv = es[g * N_ * H_ + src * 8 + hh] + ed[g * N_ * H_ + tgt * 8 + hh];
    ev = xv > 0.f ? xv : 0.2f * xv;
  }
  atomicMax(&mu[g * N_ * H_ + tgt * 8 + hh], fmap(ev));
}

__global__ void gat_edge_sum2_kernel(const int* __restrict__ topi, const int* __restrict__ boti,
                                     const float* __restrict__ es, const float* __restrict__ ed,
                                     const unsigned* __restrict__ mu, float* __restrict__ sb,
                                     float* __restrict__ p) {
  int t = blockIdx.x * 256 + threadIdx.x;
  if (t >= 2 * E_ * H_) return;
  int g = t / (E_ * H_), r = t - g * (E_ * H_);
  int e = r >> 3, hh = r & 7;
  const int* nbr = g ? boti : topi;
  int src, tgt; bool valid;
  edge_decode(e, nbr, src, tgt, valid);
  float pv = 0.f;
  if (valid) {
    float xv = es[g * N_ * H_ + src * 8 + hh] + ed[g * N_ * H_ + tgt * 8 + hh];
    float ev = xv > 0.f ? xv : 0.2f * xv;
    pv = expf(ev - funmap(mu[g * N_ * H_ + tgt * 8 + hh]));
  }
  p[t] = pv;
  if (pv != 0.f) atomicAdd(&sb[g * N_ * H_ + tgt * 8 + hh], pv);
}

__global__ void csr_zero2_kernel(int* __restrict__ deg) {
  int i = blockIdx.x * 256 + threadIdx.x;
  if (i < 2 * N_) deg[i] = 0;
}
__global__ void csr_count2_kernel(const int* __restrict__ topi, const int* __restrict__ boti,
                                  int* __restrict__ deg) {
  int e2 = blockIdx.x * 256 + threadIdx.x;
  if (e2 >= 2 * E_) return;
  int g = e2 / E_, e = e2 - g * E_;
  const int* nbr = g ? boti : topi;
  int src, tgt; bool valid;
  edge_decode(e, nbr, src, tgt, valid);
  if (valid) atomicAdd(&deg[g * N_ + tgt], 1);
}
__global__ __launch_bounds__(256)
void csr_scan2_kernel(const int* __restrict__ deg, int* __restrict__ off, int* __restrict__ cur) {
  __shared__ int red[256];
  int tid = threadIdx.x;
  int base = tid * 47;
  int loc[47];
  int s = 0;
  for (int k = 0; k < 47; k++) {
    int i = base + k;
    int v = (i < 2 * N_) ? deg[i] : 0;
    loc[k] = s; s += v;
  }
  red[tid] = s; __syncthreads();
  int total = s;
  for (int st = 1; st < 256; st <<= 1) {
    int add = (tid >= st) ? red[tid - st] : 0;
    __syncthreads();
    red[tid] += add;
    __syncthreads();
  }
  int texcl = red[tid] - total;
  for (int k = 0; k < 47; k++) {
    int i = base + k;
    if (i < 2 * N_) { int o = texcl + loc[k]; off[i] = o; cur[i] = o; }
  }
  if (tid == 255) off[2 * N_] = red[255];
}
__global__ void csr_scatter2_kernel(const int* __restrict__ topi, const int* __restrict__ boti,
                                    int* __restrict__ cur, int* __restrict__ eidx,
                                    int* __restrict__ tidx) {
  int e2 = blockIdx.x * 256 + threadIdx.x;
  if (e2 >= 2 * E_) return;
  int g = e2 / E_, e = e2 - g * E_;
  const int* nbr = g ? boti : topi;
  int src, tgt; bool valid;
  edge_decode(e, nbr, src, tgt, valid);
  if (valid) { int pos = atomicAdd(&cur[g * N_ + tgt], 1); eidx[pos] = e2; tidx[pos] = g * N_ + tgt; }
}

// load-balanced segmented aggregation over combined CSR (targets 0..2N)
__global__ __launch_bounds__(256)
void gat_seg2_kernel(const int* __restrict__ off2N, const int* __restrict__ eidx,
                     const int* __restrict__ tidx, const float* __restrict__ p,
                     const float* __restrict__ sb, const float* __restrict__ gout,
                     float* __restrict__ tobo) {
  __shared__ int se[64], st[64];
  int total = off2N[0];
  int b0 = blockIdx.x * 64;
  if (b0 >= total) return;
  int cnt = min(64, total - b0);
  int tid = threadIdx.x;
  if (tid < cnt) { se[tid] = eidx[b0 + tid]; st[tid] = tidx[b0 + tid]; }
  __syncthreads();
  int hh = tid >> 5;
  float acc = 0.f;
  int curT = st[0];
  for (int ii = 0; ii < cnt; ii++) {
    int tg = st[ii];
    if (tg != curT) {
      float invS = 1.f / (sb[curT * 8 + hh] + 1e-16f);
      atomicAdd(&tobo[(size_t)curT * 256 + tid], acc * invS);
      acc = 0.f; curT = tg;
    }
    int e2 = se[ii];
    int g = (e2 >= E_) ? 1 : 0;
    int e = e2 - g * E_;
    int src = (e < N_ * KK_) ? (e >> 5) : (e - N_ * KK_);
    float pv = p[(size_t)e2 * 8 + hh];
    acc += pv * gout[256 + 256 * g + (size_t)src * 768 + tid];
  }
  float invS = 1.f / (sb[curT * 8 + hh] + 1e-16f);
  atomicAdd(&tobo[(size_t)curT * 256 + tid], acc * invS);
}

// ---------------- gating fuse + double LN (GAT biases folded in) ----------------
__global__ __launch_bounds__(256)
void fuse_kernel(const float* __restrict__ so, const float* __restrict__ to,
                 const float* __restrict__ bo, const float* __restrict__ gatb,
                 const float* __restrict__ impW, const float* __restrict__ impb,
                 const float* __restrict__ node,
                 const float* __restrict__ gag, const float* __restrict__ gab,
                 const float* __restrict__ fing, const float* __restrict__ finb,
                 float* __restrict__ outv, int ldso) {
  __shared__ float red[256];
  size_t row = blockIdx.x;
  int tid = threadIdx.x;
  float s0 = so[row * ldso + tid];
  float t0 = to[row * 256 + tid] + gatb[256 + tid];
  float b0 = bo[row * 256 + tid] + gatb[512 + tid];
  float l0 = block_sum_256(s0 * impW[tid], red) + impb[0];
  float l1 = block_sum_256(t0 * impW[256 + tid], red) + impb[1];
  float l2 = block_sum_256(b0 * impW[512 + tid], red) + impb[2];
  float mx = fmaxf(l0, fmaxf(l1, l2));
  float e0 = expf(l0 - mx), e1 = expf(l1 - mx), e2 = expf(l2 - mx);
  float inv = 1.f / (e0 + e1 + e2);
  float fused = (e0 * s0 + e1 * t0 + e2 * b0) * inv;
  float v = geluf(fused) + node[row * 256 + tid];
  float mean = block_sum_256(v, red) * (1.f / 256.f);
  float d = v - mean;
  float var = block_sum_256(d * d, red) * (1.f / 256.f);
  float y = d * rsqrtf(var + 1e-5f) * gag[tid] + gab[tid];
  mean = block_sum_256(y, red) * (1.f / 256.f);
  d = y - mean;
  var = block_sum_256(d * d, red) * (1.f / 256.f);
  outv[row * 256 + tid] = d * rsqrtf(var + 1e-5f) * fing[tid] + finb[tid];
}

// ---------------- host launch ----------------
extern "C" void kernel_launch(void* const* d_in, const int* in_sizes, int n_in,
                              void* d_out, int out_size, void* d_ws, size_t ws_size,
                              hipStream_t stream) {
  const float* x        = (const float*)d_in[0];
  const float* gru_Wih  = (const float*)d_in[1];
  const float* gru_bih  = (const float*)d_in[2];
  const float* gru_bhh  = (const float*)d_in[3];
  const float* va_Wq    = (const float*)d_in[4];
  const float* va_bq    = (const float*)d_in[5];
  const float* va_Wk    = (const float*)d_in[6];
  const float* va_bk    = (const float*)d_in[7];
  const float* va_Wv    = (const float*)d_in[8];
  const float* va_bv    = (const float*)d_in[9];
  const float* va_lnq_g = (const float*)d_in[10];
  const float* va_lnq_b = (const float*)d_in[11];
  const float* va_lnk_g = (const float*)d_in[12];
  const float* va_lnk_b = (const float*)d_in[13];
  const float* va_lnv_g = (const float*)d_in[14];
  const float* va_lnv_b = (const float*)d_in[15];
  const float* va_Wo    = (const float*)d_in[16];
  const float* va_bo    = (const float*)d_in[17];
  const float* va_ln_g  = (const float*)d_in[18];
  const float* va_ln_b  = (const float*)d_in[19];
  const float* va_fi_W1 = (const float*)d_in[20];
  const float* va_fi_b1 = (const float*)d_in[21];
  const float* va_fi_W2 = (const float*)d_in[22];
  const float* va_fi_b2 = (const float*)d_in[23];
  const float* gat_W    = (const float*)d_in[24];
  const float* gat_asrc = (const float*)d_in[25];
  const float* gat_adst = (const float*)d_in[26];
  const float* gat_bias = (const float*)d_in[27];
  const float* imp_W    = (const float*)d_in[28];
  const float* imp_b    = (const float*)d_in[29];
  const float* ga_ln_g  = (const float*)d_in[30];
  const float* ga_ln_b  = (const float*)d_in[31];
  const float* fin_ln_g = (const float*)d_in[32];
  const float* fin_ln_b = (const float*)d_in[33];
  const float* pred_W1  = (const float*)d_in[34];
  const float* pred_b1  = (const float*)d_in[35];
  const float* pred_W2  = (const float*)d_in[36];
  const float* pred_b2  = (const float*)d_in[37];

  float* base   = (float*)d_ws;
  float* emb    = base;
  __hip_bfloat16* obuf = (__hip_bfloat16*)(base + 24576000);   // [NF,256] bf16
  float* smalls = base + 36864000;
  float* wbuf   = smalls;                                      // [NF]
  float* nodeb  = smalls + 192000;
  __hip_bfloat16* xh = (__hip_bfloat16*)(smalls + 1728000);
  __hip_bfloat16* xl = (__hip_bfloat16*)(smalls + 2496000);
  int*   topi   = (int*)(smalls + 3264000);
  int*   boti   = (int*)(smalls + 3456000);
  float* wtb    = smalls + 3648000;
  float* simb   = base;
  // post-topk overlays (dead sim region):
  float* gout   = base + 0;                   // [N,768]
  float* to     = base + 4608000;             // [N,256]
  float* bo     = base + 6144000;             // [N,256]
  float* esb    = base + 7680000;
  float* edb    = base + 7776000;
  unsigned* mu  = (unsigned*)(base + 7872000);
  float* sb     = base + 7968000;
  float* pb     = base + 8064000;             // [2EH]
  float* outv   = base + 11232000;
  int* csr_off  = (int*)(base + 12768000);
  int* csr_cur  = (int*)(base + 12782000);
  int* csr_deg  = (int*)(base + 12794000);
  int* csr_eidx = (int*)(base + 12806000);
  int* csr_tidx = (int*)(base + 13202000);

  // packed weights (inside wtb)
  __hip_bfloat16* wbf    = (__hip_bfloat16*)wtb;
  __hip_bfloat16* predtb = (__hip_bfloat16*)(wtb + 393216);
  float* qkvb   = wtb + 458752;
  float* b3     = wtb + 460288;
  __hip_bfloat16* gwh = (__hip_bfloat16*)(wtb + 461056);

  // --- weight prep
  transpose12_kernel<<<dim3(256, 12), 256, 0, stream>>>(
      va_Wq, va_Wk, va_Wv, va_Wq + 65536, va_Wk + 65536, va_Wv + 65536,
      va_Wo, va_Wo + 65536, va_fi_W1 + (L_-1) * 65536,
      gat_W, gat_W + 65536, gat_W + 131072, wbf);
  transpose_pred_kernel<<<512, 256, 0, stream>>>(pred_W1, predtb);
  biascat_kernel<<<dim3(3, 2), 256, 0, stream>>>(va_bq, va_bk, va_bv, qkvb);
  gatbias_kernel<<<3, 256, 0, stream>>>(gat_bias, b3);
  gruw_cvt_kernel<<<3072, 256, 0, stream>>>(gru_Wih, gwh);

  // --- TimeMixing GRU
  gru_mfma_kernel<<<dim3(2, 94, 16), 256, 0, stream>>>(x, gwh, gru_bih, gru_bhh, emb);

  // --- Variable attention layers: 2 dispatches per layer (2 nodes/block, 512 thr)
  for (int l = 0; l < L_; l++) {
    const __hip_bfloat16* qkvtb = wbf + (size_t)l * 3 * 65536;
    const __hip_bfloat16* wotb  = wbf + (size_t)(6 + l) * 65536;
    qkv_attn2_kernel<<<N_ / 2, 512, 0, stream>>>(emb, qkvtb, qkvb + l * 768, obuf,
                                                 va_lnq_g + l * 256, va_lnq_b + l * 256,
                                                 va_lnk_g + l * 256, va_lnk_b + l * 256,
                                                 va_lnv_g + l * 256, va_lnv_b + l * 256);
    wo_resid_ln_kernel<<<(NF_ + 63) / 64, 256, 0, stream>>>(obuf, wotb, va_bo + l * 256,
                                                            emb, va_ln_g + l * 256,
                                                            va_ln_b + l * 256, NF_);
  }

  // --- feature importance (single dispatch; +b2 dropped: softmax-invariant)
  zero_f_kernel<<<(NF_ + 255) / 256, 256, 0, stream>>>(wbuf, NF_);
  gemm_dot2<<<dim3(2, (NF_ + 127) / 128), 256, 0, stream>>>(emb, wbf + 8 * 65536,
                                                            va_fi_b1 + (L_-1) * 256,
                                                            va_fi_W2 + (L_-1) * 256,
                                                            wbuf, NF_, 256, 256);
  node_prep_kernel<<<N_, 256, 0, stream>>>(wbuf, emb, nodeb, xh, xl);

  // --- cosine similarity + top/bottom-k
  sim_split_kernel<<<dim3(47, 47), 256, 0, stream>>>(xh, xl, simb);
  topk_kernel<<<N_, 256, 0, stream>>>(simb, topi, boti);

  // --- merged self/top/bot projection GEMM -> gout [N,768]
  gemm_fA_bB<0><<<dim3(6, 47), 256, 0, stream>>>(nodeb, wbf + 9 * 65536, b3, gout, N_, 256, 768);

  // --- GAT (both graphs per dispatch)
  const int G_NH2 = (2 * N_ * H_ + 255) / 256;
  const int G_ND2 = (2 * N_ * D_ + 255) / 256;
  const int G_EH2 = (2 * E_ * H_ + 255) / 256;
  const int G_E2  = (2 * E_ + 255) / 256;
  const int G_SEG = (2 * E_ + 63) / 64;
  gat_esed2_kernel<<<G_NH2, 256, 0, stream>>>(gout, gat_asrc, gat_adst, esb, edb);
  gat_init2_kernel<<<G_ND2, 256, 0, stream>>>(mu, sb, to);
  gat_edge_max2_kernel<<<G_EH2, 256, 0, stream>>>(topi, boti, esb, edb, mu);
  gat_edge_sum2_kernel<<<G_EH2, 256, 0, stream>>>(topi, boti, esb, edb, mu, sb, pb);
  csr_zero2_kernel<<<(2 * N_ + 255) / 256, 256, 0, stream>>>(csr_deg);
  csr_count2_kernel<<<G_E2, 256, 0, stream>>>(topi, boti, csr_deg);
  csr_scan2_kernel<<<1, 256, 0, stream>>>(csr_deg, csr_off, csr_cur);
  csr_scatter2_kernel<<<G_E2, 256, 0, stream>>>(topi, boti, csr_cur, csr_eidx, csr_tidx);
  gat_seg2_kernel<<<G_SEG, 256, 0, stream>>>(csr_off + 2 * N_, csr_eidx, csr_tidx, pb, sb,
                                             gout, to);

  // --- gating fuse + double LN (GAT biases folded in)
  fuse_kernel<<<N_, 256, 0, stream>>>(gout, to, bo, gat_bias, imp_W, imp_b, nodeb,
                                      ga_ln_g, ga_ln_b, fin_ln_g, fin_ln_b, outv, 768);

  // --- predictor (fused gelu-dot; d_out seeded with pred_b2)
  init_scalar_kernel<<<(N_ + 255) / 256, 256, 0, stream>>>((float*)d_out, pred_b2, N_);
  gemm_dot2<<<dim3(4, 47), 256, 0, stream>>>(outv, predtb, pred_b1, pred_W2,
                                             (float*)d_out, N_, 256, 512);
}

// Round 19
// 1613.666 us; speedup vs baseline: 1.1872x; 1.1872x over previous
//
#include <hip/hip_runtime.h>
#include <hip/hip_bf16.h>
#include <math.h>

#define N_  6000
#define F_  16
#define S_  64
#define D_  256
#define H_  8
#define KK_ 32
#define L_  2
#define DH_ 32
#define E_  (N_*KK_ + N_)   // 198000 edges
#define NF_ (N_*F_)         // 96000 token rows

typedef float f32x4 __attribute__((ext_vector_type(4)));
typedef float f32v4 __attribute__((ext_vector_type(4)));
typedef __bf16 bf16_t;
typedef bf16_t bf16x8 __attribute__((ext_vector_type(8)));

// ---------------- device helpers ----------------

__device__ __forceinline__ float geluf(float x) {
  return 0.5f * x * (1.0f + erff(x * 0.7071067811865476f));
}
__device__ __forceinline__ float sigmf(float x) {
  return 1.0f / (1.0f + expf(-x));
}
__device__ __forceinline__ float block_sum_256(float v, float* red) {
  int tid = threadIdx.x;
  red[tid] = v; __syncthreads();
  #pragma unroll
  for (int s = 128; s > 0; s >>= 1) {
    if (tid < s) red[tid] += red[tid + s];
    __syncthreads();
  }
  float r = red[0];
  __syncthreads();
  return r;
}
__device__ __forceinline__ unsigned fmap(float f) {
  unsigned u = __float_as_uint(f);
  return (u & 0x80000000u) ? ~u : (u | 0x80000000u);
}
__device__ __forceinline__ float funmap(unsigned u) {
  unsigned b = (u & 0x80000000u) ? (u ^ 0x80000000u) : ~u;
  return __uint_as_float(b);
}

// ---------------- weight prep / small utils ----------------
__global__ void transpose12_kernel(const float* s0, const float* s1, const float* s2,
                                   const float* s3, const float* s4, const float* s5,
                                   const float* s6, const float* s7, const float* s8,
                                   const float* s9, const float* s10, const float* s11,
                                   __hip_bfloat16* __restrict__ dst) {
  int m = blockIdx.y;
  const float* src;
  switch (m) {
    case 0: src = s0; break; case 1: src = s1; break; case 2: src = s2; break;
    case 3: src = s3; break; case 4: src = s4; break; case 5: src = s5; break;
    case 6: src = s6; break; case 7: src = s7; break; case 8: src = s8; break;
    case 9: src = s9; break; case 10: src = s10; break; default: src = s11; break;
  }
  int o = blockIdx.x, i = threadIdx.x;
  dst[(size_t)m * 65536 + o * 256 + i] = __float2bfloat16(src[(size_t)i * 256 + o]);
}
__global__ void transpose_pred_kernel(const float* __restrict__ src, __hip_bfloat16* __restrict__ dst) {
  int o = blockIdx.x, i = threadIdx.x;   // [256,512] -> [512,256]
  dst[(size_t)o * 256 + i] = __float2bfloat16(src[(size_t)i * 512 + o]);
}
__global__ void biascat_kernel(const float* __restrict__ bq, const float* __restrict__ bk,
                               const float* __restrict__ bv, float* __restrict__ dst) {
  int s = blockIdx.x, l = blockIdx.y, t = threadIdx.x;
  const float* p = (s == 0) ? bq : (s == 1) ? bk : bv;
  dst[l * 768 + s * 256 + t] = p[l * 256 + t];
}
__global__ void gatbias_kernel(const float* __restrict__ gb, float* __restrict__ b3) {
  int t = blockIdx.x * 256 + threadIdx.x;
  if (t < 768) b3[t] = (t < 256) ? gb[t] : 0.f;
}
__global__ void gruw_cvt_kernel(const float* __restrict__ Wih,
                                __hip_bfloat16* __restrict__ Wh) {
  size_t idx = (size_t)blockIdx.x * 256 + threadIdx.x;  // 786432
  Wh[idx] = __float2bfloat16(Wih[idx]);
}
__global__ void zero_f_kernel(float* __restrict__ p, int n) {
  int i = blockIdx.x * 256 + threadIdx.x;
  if (i < n) p[i] = 0.f;
}
__global__ void init_scalar_kernel(float* __restrict__ p, const float* __restrict__ s, int n) {
  int i = blockIdx.x * 256 + threadIdx.x;
  if (i < n) p[i] = s[0];
}

// ---------------- GRU: single-bf16 MFMA, XOR-swizzled LDS, fused gate epilogue ----
__global__ __launch_bounds__(256)
void gru_mfma_kernel(const float* __restrict__ x,
                     const __hip_bfloat16* __restrict__ Wh,
                     const float* __restrict__ bih, const float* __restrict__ bhh,
                     float* __restrict__ emb) {
  __shared__ __align__(16) __hip_bfloat16 Ash[64 * 32];
  __shared__ __align__(16) __hip_bfloat16 Bsh[384 * 32];
  int kb = blockIdx.x, rb = blockIdx.y, f = blockIdx.z;
  int tid = threadIdx.x;
  int lane = tid & 63, wid = tid >> 6;
  int wrow = (wid & 1) * 32, wcol = (wid >> 1) * 64;
  int q = lane >> 4, m16 = lane & 15;

  f32x4 aR[2][4], aZ[2][4], aN[2][4];
  #pragma unroll
  for (int i = 0; i < 2; i++)
    #pragma unroll
    for (int j = 0; j < 4; j++) {
      aR[i][j] = (f32x4){0.f,0.f,0.f,0.f};
      aZ[i][j] = (f32x4){0.f,0.f,0.f,0.f};
      aN[i][j] = (f32x4){0.f,0.f,0.f,0.f};
    }

  for (int k0 = 0; k0 < 64; k0 += 32) {
    {
      int r = tid >> 2, ch = tid & 3;
      int gn = rb * 64 + r;
      bool ok = gn < N_;
      const float* src = x + ((size_t)gn * F_ + f) * S_ + k0 + ch * 8;
      union { __hip_bfloat16 h[8]; uint4 u; } t8;
      #pragma unroll
      for (int v = 0; v < 2; v++) {
        f32v4 d = ok ? *reinterpret_cast<const f32v4*>(src + v * 4) : (f32v4){0.f,0.f,0.f,0.f};
        t8.h[v * 4 + 0] = __float2bfloat16(d.x);
        t8.h[v * 4 + 1] = __float2bfloat16(d.y);
        t8.h[v * 4 + 2] = __float2bfloat16(d.z);
        t8.h[v * 4 + 3] = __float2bfloat16(d.w);
      }
      *reinterpret_cast<uint4*>(&Ash[r * 32 + (ch ^ (r & 3)) * 8]) = t8.u;
    }
    #pragma unroll
    for (int i = 0; i < 6; i++) {
      int cid = tid + i * 256;
      int row = cid >> 2, ch = cid & 3;
      size_t roff = ((size_t)f * 768 + (row >> 7) * 256 + kb * 128 + (row & 127)) * S_ + k0 + ch * 8;
      uint4 v = *reinterpret_cast<const uint4*>(Wh + roff);
      *reinterpret_cast<uint4*>(&Bsh[row * 32 + (ch ^ (row & 3)) * 8]) = v;
    }
    __syncthreads();
    bf16x8 ah[2];
    #pragma unroll
    for (int mt = 0; mt < 2; mt++) {
      int ar = wrow + mt * 16 + m16;
      ah[mt] = *reinterpret_cast<const bf16x8*>(&Ash[ar * 32 + (q ^ (ar & 3)) * 8]);
    }
    #pragma unroll
    for (int g = 0; g < 3; g++) {
      bf16x8 bh[4];
      #pragma unroll
      for (int nt = 0; nt < 4; nt++) {
        int br = g * 128 + wcol + nt * 16 + m16;
        bh[nt] = *reinterpret_cast<const bf16x8*>(&Bsh[br * 32 + (q ^ (br & 3)) * 8]);
      }
      #pragma unroll
      for (int mt = 0; mt < 2; mt++)
        #pragma unroll
        for (int nt = 0; nt < 4; nt++) {
          f32x4 acc = (g == 0) ? aR[mt][nt] : (g == 1) ? aZ[mt][nt] : aN[mt][nt];
          acc = __builtin_amdgcn_mfma_f32_16x16x32_bf16(ah[mt], bh[nt], acc, 0, 0, 0);
          if (g == 0) aR[mt][nt] = acc; else if (g == 1) aZ[mt][nt] = acc; else aN[mt][nt] = acc;
        }
    }
    __syncthreads();
  }
  #pragma unroll
  for (int mt = 0; mt < 2; mt++)
    #pragma unroll
    for (int nt = 0; nt < 4; nt++) {
      int k = kb * 128 + wcol + nt * 16 + m16;
      float brc = bih[f * 768 + k]       + bhh[f * 768 + k];
      float bzc = bih[f * 768 + 256 + k] + bhh[f * 768 + 256 + k];
      float bni = bih[f * 768 + 512 + k];
      float bnh = bhh[f * 768 + 512 + k];
      #pragma unroll
      for (int r4 = 0; r4 < 4; r4++) {
        int gn = rb * 64 + wrow + mt * 16 + q * 4 + r4;
        if (gn < N_) {
          float rr = sigmf(aR[mt][nt][r4] + brc);
          float zz = sigmf(aZ[mt][nt][r4] + bzc);
          float nn = tanhf(aN[mt][nt][r4] + bni + rr * bnh);
          emb[((size_t)gn * F_ + f) * D_ + k] = (1.f - zz) * nn;
        }
      }
    }
}

// ---------------- fused qkv GEMM + LN + attention (TWO nodes per block) ----------------
// Round-17 structure + restructured attention: within-wave (c, shalf, h) mapping;
// each thread computes 8 scores (full e-order, identical fp32 values) and gets the
// other 8 from its same-wave partner via shfl_xor(16) -> zero score redundancy and
// h spans only 2 values/wave (2-way LDS bank alias = free). Bit-identical output.
#define BSTRIDE 40

__device__ __forceinline__ void qkv_epilogue(f32x4 (&acc)[12], float (*tile)[772],
    const float* __restrict__ bias, __hip_bfloat16* __restrict__ out, int node,
    const float* __restrict__ gq, const float* __restrict__ bq,
    const float* __restrict__ gk, const float* __restrict__ bk,
    const float* __restrict__ gv, const float* __restrict__ bv,
    int tid, int lane, int w, int q, int m16) {
  __syncthreads();   // prior readers of this LDS region are done
  #pragma unroll
  for (int j = 0; j < 12; j++) {
    int col = (w * 12 + j) * 16 + m16;
    float bc = bias[col];
    #pragma unroll
    for (int r = 0; r < 4; r++)
      tile[q * 4 + r][col] = acc[j][r] + bc;
  }
  __syncthreads();

  // LN: 48 (row,slice) pairs, 12 per wave
  for (int ii = 0; ii < 12; ii++) {
    int sl = w * 12 + ii;
    int s = sl >> 4, f = sl & 15;
    float* p = &tile[f][s * 256];
    float4 d = *reinterpret_cast<float4*>(p + lane * 4);
    float sum = d.x + d.y + d.z + d.w;
    #pragma unroll
    for (int m = 1; m < 64; m <<= 1) sum += __shfl_xor(sum, m, 64);
    float mean = sum * (1.f / 256.f);
    float e0 = d.x - mean, e1 = d.y - mean, e2 = d.z - mean, e3 = d.w - mean;
    float sq = e0 * e0 + e1 * e1 + e2 * e2 + e3 * e3;
    #pragma unroll
    for (int m = 1; m < 64; m <<= 1) sq += __shfl_xor(sq, m, 64);
    float inv = rsqrtf(sq * (1.f / 256.f) + 1e-5f);
    const float* g  = (s == 0) ? gq : (s == 1) ? gk : gv;
    const float* bb = (s == 0) ? bq : (s == 1) ? bk : bv;
    float4 gg = *reinterpret_cast<const float4*>(g + lane * 4);
    float4 bo = *reinterpret_cast<const float4*>(bb + lane * 4);
    d.x = e0 * inv * gg.x + bo.x;
    d.y = e1 * inv * gg.y + bo.y;
    d.z = e2 * inv * gg.z + bo.z;
    d.w = e3 * inv * gg.w + bo.w;
    *reinterpret_cast<float4*>(p + lane * 4) = d;
  }
  __syncthreads();

  // attention: c = query token, shalf = s-range half (within-wave bit 4),
  // h = head ( (tid>>5)&3 | (tid>>7)<<2 ) -> 2 heads per wave
  int c = tid & 15, shalf = (tid >> 4) & 1;
  int h = ((tid >> 5) & 3) | ((tid >> 7) << 2);
  const float scale = 0.17677669529663687f;  // 1/sqrt(32)
  // own 8 scores: s = shalf*8 + j, dot order e=0..31 (identical to prior rounds)
  float own[8];
  #pragma unroll
  for (int j = 0; j < 8; j++) {
    int s = shalf * 8 + j;
    float a2 = 0.f;
    #pragma unroll
    for (int e = 0; e < 32; e++)
      a2 += tile[c][h * 32 + e] * tile[s][256 + h * 32 + e];
    own[j] = a2 * scale;
  }
  // exchange with same-wave partner (lane^16) -> full sc[16] in s-order
  float sc[16];
  #pragma unroll
  for (int j = 0; j < 8; j++) {
    float other = __shfl_xor(own[j], 16, 64);
    sc[shalf * 8 + j] = own[j];
    sc[(1 - shalf) * 8 + j] = other;
  }
  float mx = -3e38f;
  #pragma unroll
  for (int s = 0; s < 16; s++) mx = fmaxf(mx, sc[s]);
  float sum = 0.f;
  #pragma unroll
  for (int s = 0; s < 16; s++) { sc[s] = expf(sc[s] - mx); sum += sc[s]; }
  float inv = 1.f / sum;
  #pragma unroll
  for (int dd = 0; dd < 16; dd++) {
    int d = shalf * 16 + dd;
    float a2 = 0.f;
    #pragma unroll
    for (int s = 0; s < 16; s++) a2 += sc[s] * tile[s][512 + h * 32 + d];
    out[((size_t)node * 16 + c) * 256 + h * 32 + d] = __float2bfloat16(a2 * inv);
  }
}

__global__ __launch_bounds__(256, 2)
void qkv_attn2_kernel(const float* __restrict__ emb, const __hip_bfloat16* __restrict__ Wt,
                      const float* __restrict__ bias, __hip_bfloat16* __restrict__ out,
                      const float* __restrict__ gq, const float* __restrict__ bq,
                      const float* __restrict__ gk, const float* __restrict__ bk,
                      const float* __restrict__ gv, const float* __restrict__ bv) {
  __shared__ __align__(16) __hip_bfloat16 As[32 * 256];            // 16 KB
  __shared__ __align__(16) unsigned char shbuf[768 * BSTRIDE * 2]; // 61.4 KB: Bs / tile
  __hip_bfloat16* Bs = reinterpret_cast<__hip_bfloat16*>(shbuf);
  float (*tile)[772] = reinterpret_cast<float (*)[772]>(shbuf);    // 49.4 KB view
  int n0 = blockIdx.x * 2, tid = threadIdx.x;
  int lane = tid & 63, w = tid >> 6;
  int q = lane >> 4, m16 = lane & 15;

  // stage A: 32 rows x 256 cols (fp32 -> bf16), swizzle ch^(r&7)
  #pragma unroll
  for (int i = 0; i < 4; i++) {
    int cid = tid + i * 256;           // 0..1023
    int r = cid >> 5, ch = cid & 31;
    const float* src = emb + ((size_t)n0 * 16 + r) * 256 + ch * 8;
    union { __hip_bfloat16 h[8]; uint4 u; } t8;
    #pragma unroll
    for (int v = 0; v < 2; v++) {
      f32v4 d = *reinterpret_cast<const f32v4*>(src + v * 4);
      t8.h[v * 4 + 0] = __float2bfloat16(d.x);
      t8.h[v * 4 + 1] = __float2bfloat16(d.y);
      t8.h[v * 4 + 2] = __float2bfloat16(d.z);
      t8.h[v * 4 + 3] = __float2bfloat16(d.w);
    }
    *reinterpret_cast<uint4*>(&As[r * 256 + (ch ^ (r & 7)) * 8]) = t8.u;
  }

  // GEMM: wave w owns n-tiles w*12..w*12+11 for both nodes; K=256 in 8 k-slices
  f32x4 acc0[12], acc1[12];
  #pragma unroll
  for (int j = 0; j < 12; j++) {
    acc0[j] = (f32x4){0.f,0.f,0.f,0.f};
    acc1[j] = (f32x4){0.f,0.f,0.f,0.f};
  }
  for (int k = 0; k < 8; k++) {
    __syncthreads();   // protect Bs from previous iteration's readers
    // stage B k-slice: 768 rows x 32 cols, stride-40 rows, 12 chunk-stores/thread
    #pragma unroll
    for (int i = 0; i < 12; i++) {
      int cid = tid + i * 256;
      int row = cid >> 2, ch = cid & 3;
      uint4 v = *reinterpret_cast<const uint4*>(Wt + (size_t)row * 256 + k * 32 + ch * 8);
      *reinterpret_cast<uint4*>(&Bs[row * BSTRIDE + ch * 8]) = v;
    }
    __syncthreads();
    int c = k * 4 + q;
    bf16x8 a0 = *reinterpret_cast<const bf16x8*>(&As[m16 * 256 + (c ^ (m16 & 7)) * 8]);
    bf16x8 a1 = *reinterpret_cast<const bf16x8*>(&As[(16 + m16) * 256 + (c ^ (m16 & 7)) * 8]);
    #pragma unroll
    for (int j = 0; j < 12; j++) {
      int br = (w * 12 + j) * 16 + m16;
      bf16x8 b = *reinterpret_cast<const bf16x8*>(&Bs[br * BSTRIDE + q * 8]);
      acc0[j] = __builtin_amdgcn_mfma_f32_16x16x32_bf16(a0, b, acc0[j], 0, 0, 0);
      acc1[j] = __builtin_amdgcn_mfma_f32_16x16x32_bf16(a1, b, acc1[j], 0, 0, 0);
    }
  }

  // per-node epilogues (constant indexing after inlining)
  qkv_epilogue(acc0, tile, bias, out, n0,     gq, bq, gk, bk, gv, bv, tid, lane, w, q, m16);
  qkv_epilogue(acc1, tile, bias, out, n0 + 1, gq, bq, gk, bk, gv, bv, tid, lane, w, q, m16);
}

// ---------------- MFMA GEMM: A fp32 (cvt), B pre-bf16 [Nt,K] ----------------
template <int EPI>
__global__ __launch_bounds__(256)
void gemm_fA_bB(const float* __restrict__ A, const __hip_bfloat16* __restrict__ Btb,
                const float* __restrict__ bias, float* __restrict__ C,
                int M, int K, int Nt) {
  __shared__ __align__(16) __hip_bfloat16 As[128 * 32];
  __shared__ __align__(16) __hip_bfloat16 Bs[128 * 32];
  int mb = blockIdx.y * 128, nb = blockIdx.x * 128;
  int tid = threadIdx.x;
  int lane = tid & 63, wid = tid >> 6;
  int wm = (wid >> 1) * 64, wn = (wid & 1) * 64;
  int q = lane >> 4, m16 = lane & 15;
  int arow = tid >> 1;
  int acol = (tid & 1) * 16;

  f32x4 acc[4][4];
  #pragma unroll
  for (int i = 0; i < 4; i++)
    #pragma unroll
    for (int j = 0; j < 4; j++) acc[i][j] = (f32x4){0.f, 0.f, 0.f, 0.f};

  uint4 z4 = {0u,0u,0u,0u};
  for (int k0 = 0; k0 < K; k0 += 32) {
    {
      bool ok = (mb + arow) < M;
      const float* src = A + (size_t)(mb + arow) * K + k0 + acol;
      union { __hip_bfloat16 h[16]; uint4 u[2]; } tmp;
      #pragma unroll
      for (int v = 0; v < 4; v++) {
        f32v4 d = ok ? *reinterpret_cast<const f32v4*>(src + v * 4) : (f32v4){0.f,0.f,0.f,0.f};
        tmp.h[v * 4 + 0] = __float2bfloat16(d.x);
        tmp.h[v * 4 + 1] = __float2bfloat16(d.y);
        tmp.h[v * 4 + 2] = __float2bfloat16(d.z);
        tmp.h[v * 4 + 3] = __float2bfloat16(d.w);
      }
      uint4* dst = reinterpret_cast<uint4*>(&As[arow * 32 + acol]);
      dst[0] = tmp.u[0]; dst[1] = tmp.u[1];
    }
    {
      bool ok = (nb + arow) < Nt;
      const uint4* src = reinterpret_cast<const uint4*>(Btb + (size_t)(nb + arow) * K + k0 + acol);
      uint4* dst = reinterpret_cast<uint4*>(&Bs[arow * 32 + acol]);
      dst[0] = ok ? src[0] : z4; dst[1] = ok ? src[1] : z4;
    }
    __syncthreads();
    bf16x8 av[4], bv[4];
    #pragma unroll
    for (int mt = 0; mt < 4; mt++)
      av[mt] = *reinterpret_cast<const bf16x8*>(&As[(wm + mt * 16 + m16) * 32 + q * 8]);
    #pragma unroll
    for (int nt = 0; nt < 4; nt++)
      bv[nt] = *reinterpret_cast<const bf16x8*>(&Bs[(wn + nt * 16 + m16) * 32 + q * 8]);
    #pragma unroll
    for (int mt = 0; mt < 4; mt++)
      #pragma unroll
      for (int nt = 0; nt < 4; nt++)
        acc[mt][nt] = __builtin_amdgcn_mfma_f32_16x16x32_bf16(av[mt], bv[nt], acc[mt][nt], 0, 0, 0);
    __syncthreads();
  }
  #pragma unroll
  for (int mt = 0; mt < 4; mt++) {
    #pragma unroll
    for (int nt = 0; nt < 4; nt++) {
      #pragma unroll
      for (int r = 0; r < 4; r++) {
        int row = mb + wm + mt * 16 + q * 4 + r;
        int col = nb + wn + nt * 16 + m16;
        if (row < M && col < Nt) {
          float c = acc[mt][nt][r] + (bias ? bias[col] : 0.f);
          if (EPI == 1) c = geluf(c);
          C[(size_t)row * Nt + col] = c;
        }
      }
    }
  }
}

// ---- GEMM + fused gelu-dot epilogue (A fp32, B pre-bf16) ----
__global__ __launch_bounds__(256)
void gemm_dot2(const float* __restrict__ A, const __hip_bfloat16* __restrict__ Btb,
               const float* __restrict__ bias, const float* __restrict__ w2,
               float* __restrict__ out1, int M, int K, int Nt) {
  __shared__ __align__(16) __hip_bfloat16 As[128 * 32];
  __shared__ __align__(16) __hip_bfloat16 Bs[128 * 32];
  int mb = blockIdx.y * 128, nb = blockIdx.x * 128;
  int tid = threadIdx.x;
  int lane = tid & 63, wid = tid >> 6;
  int wm = (wid >> 1) * 64, wn = (wid & 1) * 64;
  int q = lane >> 4, m16 = lane & 15;
  int arow = tid >> 1;
  int acol = (tid & 1) * 16;

  f32x4 acc[4][4];
  #pragma unroll
  for (int i = 0; i < 4; i++)
    #pragma unroll
    for (int j = 0; j < 4; j++) acc[i][j] = (f32x4){0.f, 0.f, 0.f, 0.f};

  uint4 z4 = {0u,0u,0u,0u};
  for (int k0 = 0; k0 < K; k0 += 32) {
    {
      bool ok = (mb + arow) < M;
      const float* src = A + (size_t)(mb + arow) * K + k0 + acol;
      union { __hip_bfloat16 h[16]; uint4 u[2]; } tmp;
      #pragma unroll
      for (int v = 0; v < 4; v++) {
        f32v4 d = ok ? *reinterpret_cast<const f32v4*>(src + v * 4) : (f32v4){0.f,0.f,0.f,0.f};
        tmp.h[v * 4 + 0] = __float2bfloat16(d.x);
        tmp.h[v * 4 + 1] = __float2bfloat16(d.y);
        tmp.h[v * 4 + 2] = __float2bfloat16(d.z);
        tmp.h[v * 4 + 3] = __float2bfloat16(d.w);
      }
      uint4* dst = reinterpret_cast<uint4*>(&As[arow * 32 + acol]);
      dst[0] = tmp.u[0]; dst[1] = tmp.u[1];
    }
    {
      bool ok = (nb + arow) < Nt;
      const uint4* src = reinterpret_cast<const uint4*>(Btb + (size_t)(nb + arow) * K + k0 + acol);
      uint4* dst = reinterpret_cast<uint4*>(&Bs[arow * 32 + acol]);
      dst[0] = ok ? src[0] : z4; dst[1] = ok ? src[1] : z4;
    }
    __syncthreads();
    bf16x8 av[4], bv[4];
    #pragma unroll
    for (int mt = 0; mt < 4; mt++)
      av[mt] = *reinterpret_cast<const bf16x8*>(&As[(wm + mt * 16 + m16) * 32 + q * 8]);
    #pragma unroll
    for (int nt = 0; nt < 4; nt++)
      bv[nt] = *reinterpret_cast<const bf16x8*>(&Bs[(wn + nt * 16 + m16) * 32 + q * 8]);
    #pragma unroll
    for (int mt = 0; mt < 4; mt++)
      #pragma unroll
      for (int nt = 0; nt < 4; nt++)
        acc[mt][nt] = __builtin_amdgcn_mfma_f32_16x16x32_bf16(av[mt], bv[nt], acc[mt][nt], 0, 0, 0);
    __syncthreads();
  }
  #pragma unroll
  for (int mt = 0; mt < 4; mt++) {
    #pragma unroll
    for (int r = 0; r < 4; r++) {
      int row = mb + wm + mt * 16 + q * 4 + r;
      float s = 0.f;
      #pragma unroll
      for (int nt = 0; nt < 4; nt++) {
        int col = nb + wn + nt * 16 + m16;
        float c = geluf(acc[mt][nt][r] + bias[col]);
        s += c * w2[col];
      }
      #pragma unroll
      for (int m = 1; m < 16; m <<= 1) s += __shfl_xor(s, m, 64);
      if (m16 == 0 && row < M) atomicAdd(&out1[row], s);
    }
  }
}

// ---- fused Wo GEMM + gelu residual + LN: emb = LN(gelu(obuf@Wo^T + bo) + emb) ----
__global__ __launch_bounds__(256)
void wo_resid_ln_kernel(const __hip_bfloat16* __restrict__ A, const __hip_bfloat16* __restrict__ Btb,
                        const float* __restrict__ bias, float* __restrict__ emb,
                        const float* __restrict__ g, const float* __restrict__ b, int M) {
  __shared__ __align__(16) __hip_bfloat16 As[64 * 32];
  __shared__ __align__(16) __hip_bfloat16 Bs[256 * 32];
  int mb = blockIdx.x * 64;
  int tid = threadIdx.x, lane = tid & 63, w = tid >> 6;
  int q = lane >> 4, m16 = lane & 15;
  f32x4 acc[16];
  #pragma unroll
  for (int nt = 0; nt < 16; nt++) acc[nt] = (f32x4){0.f,0.f,0.f,0.f};
  uint4 z4 = {0u,0u,0u,0u};
  for (int k0 = 0; k0 < 256; k0 += 32) {
    { int r = tid >> 2, c0 = (tid & 3) * 8;
      int gr = mb + r;
      uint4 v = (gr < M) ? *reinterpret_cast<const uint4*>(A + (size_t)gr * 256 + k0 + c0) : z4;
      *reinterpret_cast<uint4*>(&As[r * 32 + c0]) = v; }
    { const uint4* src = reinterpret_cast<const uint4*>(Btb + (size_t)tid * 256 + k0);
      uint4* dst = reinterpret_cast<uint4*>(&Bs[tid * 32]);
      dst[0] = src[0]; dst[1] = src[1]; dst[2] = src[2]; dst[3] = src[3]; }
    __syncthreads();
    bf16x8 av = *reinterpret_cast<const bf16x8*>(&As[(w * 16 + m16) * 32 + q * 8]);
    #pragma unroll
    for (int nt = 0; nt < 16; nt++) {
      bf16x8 bv = *reinterpret_cast<const bf16x8*>(&Bs[(nt * 16 + m16) * 32 + q * 8]);
      acc[nt] = __builtin_amdgcn_mfma_f32_16x16x32_bf16(av, bv, acc[nt], 0, 0, 0);
    }
    __syncthreads();
  }
  #pragma unroll
  for (int r = 0; r < 4; r++) {
    int grow = mb + w * 16 + q * 4 + r;
    if (grow >= M) continue;     // uniform within each 16-lane group
    float s = 0.f;
    #pragma unroll
    for (int nt = 0; nt < 16; nt++) {
      int col = nt * 16 + m16;
      float v = geluf(acc[nt][r] + bias[col]) + emb[(size_t)grow * 256 + col];
      acc[nt][r] = v; s += v;
    }
    #pragma unroll
    for (int m = 1; m < 16; m <<= 1) s += __shfl_xor(s, m, 64);
    float mean = s * (1.f / 256.f);
    float sq = 0.f;
    #pragma unroll
    for (int nt = 0; nt < 16; nt++) { float d = acc[nt][r] - mean; sq += d * d; }
    #pragma unroll
    for (int m = 1; m < 16; m <<= 1) sq += __shfl_xor(sq, m, 64);
    float inv = rsqrtf(sq * (1.f / 256.f) + 1e-5f);
    #pragma unroll
    for (int nt = 0; nt < 16; nt++) {
      int col = nt * 16 + m16;
      emb[(size_t)grow * 256 + col] = (acc[nt][r] - mean) * inv * g[col] + b[col];
    }
  }
}

// ---------------- split-bf16 sim GEMM ----------------
__global__ __launch_bounds__(256)
void sim_split_kernel(const __hip_bfloat16* __restrict__ xh, const __hip_bfloat16* __restrict__ xl,
                      float* __restrict__ C) {
  __shared__ __align__(16) __hip_bfloat16 Ah[128 * 32];
  __shared__ __align__(16) __hip_bfloat16 Al[128 * 32];
  __shared__ __align__(16) __hip_bfloat16 Bh[128 * 32];
  __shared__ __align__(16) __hip_bfloat16 Bl[128 * 32];
  int mb = blockIdx.y * 128, nb = blockIdx.x * 128;
  int tid = threadIdx.x;
  int lane = tid & 63, wid = tid >> 6;
  int wm = (wid >> 1) * 64, wn = (wid & 1) * 64;
  int q = lane >> 4, m16 = lane & 15;
  int row = tid >> 1, halfk = (tid & 1) * 16;

  f32x4 acc[4][4];
  #pragma unroll
  for (int i = 0; i < 4; i++)
    #pragma unroll
    for (int j = 0; j < 4; j++) acc[i][j] = (f32x4){0.f, 0.f, 0.f, 0.f};

  uint4 z = {0u, 0u, 0u, 0u};
  for (int k0 = 0; k0 < 256; k0 += 32) {
    {
      int gr = mb + row; bool ok = gr < N_;
      const uint4* sh = reinterpret_cast<const uint4*>(xh + (size_t)gr * 256 + k0 + halfk);
      const uint4* sl = reinterpret_cast<const uint4*>(xl + (size_t)gr * 256 + k0 + halfk);
      uint4* dh = reinterpret_cast<uint4*>(&Ah[row * 32 + halfk]);
      uint4* dl = reinterpret_cast<uint4*>(&Al[row * 32 + halfk]);
      dh[0] = ok ? sh[0] : z; dh[1] = ok ? sh[1] : z;
      dl[0] = ok ? sl[0] : z; dl[1] = ok ? sl[1] : z;
    }
    {
      int gc = nb + row; bool ok = gc < N_;
      const uint4* sh = reinterpret_cast<const uint4*>(xh + (size_t)gc * 256 + k0 + halfk);
      const uint4* sl = reinterpret_cast<const uint4*>(xl + (size_t)gc * 256 + k0 + halfk);
      uint4* dh = reinterpret_cast<uint4*>(&Bh[row * 32 + halfk]);
      uint4* dl = reinterpret_cast<uint4*>(&Bl[row * 32 + halfk]);
      dh[0] = ok ? sh[0] : z; dh[1] = ok ? sh[1] : z;
      dl[0] = ok ? sl[0] : z; dl[1] = ok ? sl[1] : z;
    }
    __syncthreads();
    bf16x8 avh[4], avl[4], bvh[4], bvl[4];
    #pragma unroll
    for (int mt = 0; mt < 4; mt++) {
      avh[mt] = *reinterpret_cast<const bf16x8*>(&Ah[(wm + mt * 16 + m16) * 32 + q * 8]);
      avl[mt] = *reinterpret_cast<const bf16x8*>(&Al[(wm + mt * 16 + m16) * 32 + q * 8]);
    }
    #pragma unroll
    for (int nt = 0; nt < 4; nt++) {
      bvh[nt] = *reinterpret_cast<const bf16x8*>(&Bh[(wn + nt * 16 + m16) * 32 + q * 8]);
      bvl[nt] = *reinterpret_cast<const bf16x8*>(&Bl[(wn + nt * 16 + m16) * 32 + q * 8]);
    }
    #pragma unroll
    for (int mt = 0; mt < 4; mt++)
      #pragma unroll
      for (int nt = 0; nt < 4; nt++) {
        acc[mt][nt] = __builtin_amdgcn_mfma_f32_16x16x32_bf16(avh[mt], bvh[nt], acc[mt][nt], 0, 0, 0);
        acc[mt][nt] = __builtin_amdgcn_mfma_f32_16x16x32_bf16(avh[mt], bvl[nt], acc[mt][nt], 0, 0, 0);
        acc[mt][nt] = __builtin_amdgcn_mfma_f32_16x16x32_bf16(avl[mt], bvh[nt], acc[mt][nt], 0, 0, 0);
      }
    __syncthreads();
  }
  #pragma unroll
  for (int mt = 0; mt < 4; mt++)
    #pragma unroll
    for (int nt = 0; nt < 4; nt++)
      #pragma unroll
      for (int r = 0; r < 4; r++) {
        int rr = mb + wm + mt * 16 + q * 4 + r;
        int cc = nb + wn + nt * 16 + m16;
        if (rr < N_ && cc < N_) C[(size_t)rr * N_ + cc] = acc[mt][nt][r];
      }
}

// ---------------- fused fi-softmax + node pooling + l2norm/split ----------------
__global__ __launch_bounds__(256)
void node_prep_kernel(const float* __restrict__ wbuf, const float* __restrict__ emb,
                      float* __restrict__ node, __hip_bfloat16* __restrict__ xh,
                      __hip_bfloat16* __restrict__ xl) {
  __shared__ float wsh[16];
  __shared__ float red[256];
  int n = blockIdx.x, tid = threadIdx.x;
  if (tid < 16) wsh[tid] = wbuf[n * 16 + tid];
  __syncthreads();
  float mx = -3e38f;
  #pragma unroll
  for (int f = 0; f < 16; f++) mx = fmaxf(mx, wsh[f]);
  float e[16], ssum = 0.f;
  #pragma unroll
  for (int f = 0; f < 16; f++) { e[f] = expf(wsh[f] - mx); ssum += e[f]; }
  float inv = 1.f / ssum;
  float acc = 0.f;
  #pragma unroll
  for (int f = 0; f < 16; f++)
    acc += e[f] * emb[((size_t)n * 16 + f) * 256 + tid];
  acc *= inv;
  node[(size_t)n * 256 + tid] = acc;
  float ss = block_sum_256(acc * acc, red);
  float y = acc * rsqrtf(ss + 1e-12f);
  __hip_bfloat16 h = __float2bfloat16(y);
  xh[(size_t)n * 256 + tid] = h;
  xl[(size_t)n * 256 + tid] = __float2bfloat16(y - __bfloat162float(h));
}

// ---------------- top-k / bottom-k: early-exit dual-pass bitwise binary search ----------------
__global__ __launch_bounds__(256)
void topk_kernel(const float* __restrict__ sim, int* __restrict__ top,
                 int* __restrict__ bot) {
  __shared__ unsigned wsum[2][4];
  __shared__ unsigned short tie[1024];
  __shared__ unsigned s_out, s_tcnt;
  int i = blockIdx.x, tid = threadIdx.x;
  int lane = tid & 63, wid = tid >> 6;
  unsigned raw[24];
  unsigned validmask = 0;
  #pragma unroll
  for (int k = 0; k < 24; k++) {
    int j = tid + k * 256;
    bool ok = (j < N_) && (j != i);
    raw[k] = ok ? fmap(sim[(size_t)i * N_ + j]) : 0u;
    validmask |= (ok ? 1u : 0u) << k;
  }
  unsigned match_t = validmask, match_b = validmask;
  unsigned sel_t = 0, sel_b = 0;
  unsigned r_t = KK_, r_b = KK_;
  bool act_t = true, act_b = true;
  for (int bit = 31; bit >= 0; bit--) {
    unsigned bmask = 0;
    #pragma unroll
    for (int k = 0; k < 24; k++) bmask |= ((raw[k] >> bit) & 1u) << k;
    unsigned effb = (~bmask) & 0x00ffffffu;
    unsigned packed = (unsigned)__popc(match_t & bmask) |
                      ((unsigned)__popc(match_b & effb) << 16);
    #pragma unroll
    for (int m = 1; m < 64; m <<= 1) packed += (unsigned)__shfl_xor((int)packed, m, 64);
    if (lane == 0) wsum[bit & 1][wid] = packed;
    __syncthreads();
    unsigned tot = wsum[bit & 1][0] + wsum[bit & 1][1] + wsum[bit & 1][2] + wsum[bit & 1][3];
    unsigned tt = tot & 0xffffu, tb = tot >> 16;
    if (act_t) {
      if (tt >= r_t) {
        match_t &= bmask;
        if (tt == r_t) { sel_t |= match_t; act_t = false; }
      } else { sel_t |= match_t & bmask; r_t -= tt; match_t &= ~bmask; }
    }
    if (act_b) {
      if (tb >= r_b) {
        match_b &= effb;
        if (tb == r_b) { sel_b |= match_b; act_b = false; }
      } else { sel_b |= match_b & effb; r_b -= tb; match_b &= ~effb; }
    }
    if (!(act_t || act_b)) break;
  }
  for (int pass = 0; pass < 2; pass++) {
    int* dst = pass ? bot : top;
    unsigned sel = pass ? sel_b : sel_t;
    unsigned match = pass ? match_b : match_t;
    bool act = pass ? act_b : act_t;        // block-uniform
    unsigned r = pass ? r_b : r_t;
    if (tid == 0) { s_out = 0; s_tcnt = 0; }
    __syncthreads();
    unsigned s = sel;
    while (s) {
      int k = __ffs(s) - 1; s &= s - 1;
      unsigned p = atomicAdd(&s_out, 1u);
      dst[i * KK_ + p] = tid + k * 256;
    }
    if (act) {
      unsigned m0 = match;
      while (m0) {
        int k = __ffs(m0) - 1; m0 &= m0 - 1;
        unsigned qx = atomicAdd(&s_tcnt, 1u);
        if (qx < 1024u) tie[qx] = (unsigned short)(tid + k * 256);
      }
    }
    __syncthreads();
    if (act) {   // rare exact-tie path: take r lowest indices
      int tcnt = (int)min(s_tcnt, 1024u);
      int basep = KK_ - (int)r;
      int last = -1;
      for (int t = 0; t < (int)r; t++) {
        unsigned best = 0xffffffffu;
        for (int idx = tid; idx < tcnt; idx += 256) {
          int j = (int)tie[idx];
          if (j > last && (unsigned)j < best) best = (unsigned)j;
        }
        #pragma unroll
        for (int m = 1; m < 64; m <<= 1) best = min(best, (unsigned)__shfl_xor((int)best, m, 64));
        if (lane == 0) wsum[t & 1][wid] = best;
        __syncthreads();
        best = min(min(wsum[t & 1][0], wsum[t & 1][1]), min(wsum[t & 1][2], wsum[t & 1][3]));
        last = (int)best;
        if (tid == 0) dst[i * KK_ + basep + t] = last;
        __syncthreads();
      }
    }
    __syncthreads();
  }
}

// ---------------- GAT (both graphs per dispatch) ----------------
__device__ __forceinline__ void edge_decode(int e, const int* nbr, int& src, int& tgt, bool& valid) {
  if (e < N_ * KK_) { src = e >> 5; tgt = nbr[e]; valid = (src != tgt); }
  else { src = tgt = e - N_ * KK_; valid = true; }
}

__global__ void gat_esed2_kernel(const float* __restrict__ gout, const float* __restrict__ asrc,
                                 const float* __restrict__ adst,
                                 float* __restrict__ es, float* __restrict__ ed) {
  int idx = blockIdx.x * 256 + threadIdx.x;
  if (idx >= 2 * N_ * H_) return;
  int g = idx / (N_ * H_), r = idx - g * (N_ * H_);
  int hh = r & 7, node = r >> 3;
  const float* hp = gout + 256 + 256 * g + (size_t)node * 768 + hh * 32;
  const float* as = asrc + 256 + 256 * g + hh * 32;
  const float* ad = adst + 256 + 256 * g + hh * 32;
  float a = 0.f, b = 0.f;
  for (int d = 0; d < 32; d++) { float hv = hp[d]; a += hv * as[d]; b += hv * ad[d]; }
  es[idx] = a; ed[idx] = b;
}

__global__ void gat_init2_kernel(unsigned* __restrict__ mu, float* __restrict__ sb,
                                 float* __restrict__ tobo) {
  int idx = blockIdx.x * 256 + threadIdx.x;
  if (idx < 2 * N_ * H_) { mu[idx] = fmap(-1e9f); sb[idx] = 0.f; }
  if (idx < 2 * N_ * D_) tobo[idx] = 0.f;
}

__global__ void gat_edge_max2_kernel(const int* __restrict__ topi, const int* __restrict__ boti,
                                     const float* __restrict__ es, const float* __restrict__ ed,
                                     unsigned* __restrict__ mu) {
  int t = blockIdx.x * 256 + threadIdx.x;
  if (t >= 2 * E_ * H_) return;
  int g = t / (E_ * H_), r = t - g * (E_ * H_);
  int e = r >> 3, hh = r & 7;
  const int* nbr = g ? boti : topi;
  int src, tgt; bool valid;
  edge_decode(e, nbr, src, tgt, valid);
  float ev = -1e9f;
  if (valid) {
    float xv = es[g * N_ * H_ + src * 8 + hh] + ed[g * N_ * H_ + tgt * 8 + hh];
    ev = xv > 0.f ? xv : 0.2f * xv;
  }
  atomicMax(&mu[g * N_ * H_ + tgt * 8 + hh], fmap(ev));
}

__global__ void gat_edge_sum2_kernel(const int* __restrict__ topi, const int* __restrict__ boti,
                                     const float* __restrict__ es, const float* __restrict__ ed,
                                     const unsigned* __restrict__ mu, float* __restrict__ sb,
                                     float* __restrict__ p) {
  int t = blockIdx.x * 256 + threadIdx.x;
  if (t >= 2 * E_ * H_) return;
  int g = t / (E_ * H_), r = t - g * (E_ * H_);
  int e = r >> 3, hh = r & 7;
  const int* nbr = g ? boti : topi;
  int src, tgt; bool valid;
  edge_decode(e, nbr, src, tgt, valid);
  float pv = 0.f;
  if (valid) {
    float xv = es[g * N_ * H_ + src * 8 + hh] + ed[g * N_ * H_ + tgt * 8 + hh];
    float ev = xv > 0.f ? xv : 0.2f * xv;
    pv = expf(ev - funmap(mu[g * N_ * H_ + tgt * 8 + hh]));
  }
  p[t] = pv;
  if (pv != 0.f) atomicAdd(&sb[g * N_ * H_ + tgt * 8 + hh], pv);
}

__global__ void csr_zero2_kernel(int* __restrict__ deg) {
  int i = blockIdx.x * 256 + threadIdx.x;
  if (i < 2 * N_) deg[i] = 0;
}
__global__ void csr_count2_kernel(const int* __restrict__ topi, const int* __restrict__ boti,
                                  int* __restrict__ deg) {
  int e2 = blockIdx.x * 256 + threadIdx.x;
  if (e2 >= 2 * E_) return;
  int g = e2 / E_, e = e2 - g * E_;
  const int* nbr = g ? boti : topi;
  int src, tgt; bool valid;
  edge_decode(e, nbr, src, tgt, valid);
  if (valid) atomicAdd(&deg[g * N_ + tgt], 1);
}
__global__ __launch_bounds__(256)
void csr_scan2_kernel(const int* __restrict__ deg, int* __restrict__ off, int* __restrict__ cur) {
  __shared__ int red[256];
  int tid = threadIdx.x;
  int base = tid * 47;
  int loc[47];
  int s = 0;
  for (int k = 0; k < 47; k++) {
    int i = base + k;
    int v = (i < 2 * N_) ? deg[i] : 0;
    loc[k] = s; s += v;
  }
  red[tid] = s; __syncthreads();
  int total = s;
  for (int st = 1; st < 256; st <<= 1) {
    int add = (tid >= st) ? red[tid - st] : 0;
    __syncthreads();
    red[tid] += add;
    __syncthreads();
  }
  int texcl = red[tid] - total;
  for (int k = 0; k < 47; k++) {
    int i = base + k;
    if (i < 2 * N_) { int o = texcl + loc[k]; off[i] = o; cur[i] = o; }
  }
  if (tid == 255) off[2 * N_] = red[255];
}
__global__ void csr_scatter2_kernel(const int* __restrict__ topi, const int* __restrict__ boti,
                                    int* __restrict__ cur, int* __restrict__ eidx,
                                    int* __restrict__ tidx) {
  int e2 = blockIdx.x * 256 + threadIdx.x;
  if (e2 >= 2 * E_) return;
  int g = e2 / E_, e = e2 - g * E_;
  const int* nbr = g ? boti : topi;
  int src, tgt; bool valid;
  edge_decode(e, nbr, src, tgt, valid);
  if (valid) { int pos = atomicAdd(&cur[g * N_ + tgt], 1); eidx[pos] = e2; tidx[pos] = g * N_ + tgt; }
}

// load-balanced segmented aggregation over combined CSR (targets 0..2N)
__global__ __launch_bounds__(256)
void gat_seg2_kernel(const int* __restrict__ off2N, const int* __restrict__ eidx,
                     const int* __restrict__ tidx, const float* __restrict__ p,
                     const float* __restrict__ sb, const float* __restrict__ gout,
                     float* __restrict__ tobo) {
  __shared__ int se[64], st[64];
  int total = off2N[0];
  int b0 = blockIdx.x * 64;
  if (b0 >= total) return;
  int cnt = min(64, total - b0);
  int tid = threadIdx.x;
  if (tid < cnt) { se[tid] = eidx[b0 + tid]; st[tid] = tidx[b0 + tid]; }
  __syncthreads();
  int hh = tid >> 5;
  float acc = 0.f;
  int curT = st[0];
  for (int ii = 0; ii < cnt; ii++) {
    int tg = st[ii];
    if (tg != curT) {
      float invS = 1.f / (sb[curT * 8 + hh] + 1e-16f);
      atomicAdd(&tobo[(size_t)curT * 256 + tid], acc * invS);
      acc = 0.f; curT = tg;
    }
    int e2 = se[ii];
    int g = (e2 >= E_) ? 1 : 0;
    int e = e2 - g * E_;
    int src = (e < N_ * KK_) ? (e >> 5) : (e - N_ * KK_);
    float pv = p[(size_t)e2 * 8 + hh];
    acc += pv * gout[256 + 256 * g + (size_t)src * 768 + tid];
  }
  float invS = 1.f / (sb[curT * 8 + hh] + 1e-16f);
  atomicAdd(&tobo[(size_t)curT * 256 + tid], acc * invS);
}

// ---------------- gating fuse + double LN (GAT biases folded in) ----------------
__global__ __launch_bounds__(256)
void fuse_kernel(const float* __restrict__ so, const float* __restrict__ to,
                 const float* __restrict__ bo, const float* __restrict__ gatb,
                 const float* __restrict__ impW, const float* __restrict__ impb,
                 const float* __restrict__ node,
                 const float* __restrict__ gag, const float* __restrict__ gab,
                 const float* __restrict__ fing, const float* __restrict__ finb,
                 float* __restrict__ outv, int ldso) {
  __shared__ float red[256];
  size_t row = blockIdx.x;
  int tid = threadIdx.x;
  float s0 = so[row * ldso + tid];
  float t0 = to[row * 256 + tid] + gatb[256 + tid];
  float b0 = bo[row * 256 + tid] + gatb[512 + tid];
  float l0 = block_sum_256(s0 * impW[tid], red) + impb[0];
  float l1 = block_sum_256(t0 * impW[256 + tid], red) + impb[1];
  float l2 = block_sum_256(b0 * impW[512 + tid], red) + impb[2];
  float mx = fmaxf(l0, fmaxf(l1, l2));
  float e0 = expf(l0 - mx), e1 = expf(l1 - mx), e2 = expf(l2 - mx);
  float inv = 1.f / (e0 + e1 + e2);
  float fused = (e0 * s0 + e1 * t0 + e2 * b0) * inv;
  float v = geluf(fused) + node[row * 256 + tid];
  float mean = block_sum_256(v, red) * (1.f / 256.f);
  float d = v - mean;
  float var = block_sum_256(d * d, red) * (1.f / 256.f);
  float y = d * rsqrtf(var + 1e-5f) * gag[tid] + gab[tid];
  mean = block_sum_256(y, red) * (1.f / 256.f);
  d = y - mean;
  var = block_sum_256(d * d, red) * (1.f / 256.f);
  outv[row * 256 + tid] = d * rsqrtf(var + 1e-5f) * fing[tid] + finb[tid];
}

// ---------------- host launch ----------------
extern "C" void kernel_launch(void* const* d_in, const int* in_sizes, int n_in,
                              void* d_out, int out_size, void* d_ws, size_t ws_size,
                              hipStream_t stream) {
  const float* x        = (const float*)d_in[0];
  const float* gru_Wih  = (const float*)d_in[1];
  const float* gru_bih  = (const float*)d_in[2];
  const float* gru_bhh  = (const float*)d_in[3];
  const float* va_Wq    = (const float*)d_in[4];
  const float* va_bq    = (const float*)d_in[5];
  const float* va_Wk    = (const float*)d_in[6];
  const float* va_bk    = (const float*)d_in[7];
  const float* va_Wv    = (const float*)d_in[8];
  const float* va_bv    = (const float*)d_in[9];
  const float* va_lnq_g = (const float*)d_in[10];
  const float* va_lnq_b = (const float*)d_in[11];
  const float* va_lnk_g = (const float*)d_in[12];
  const float* va_lnk_b = (const float*)d_in[13];
  const float* va_lnv_g = (const float*)d_in[14];
  const float* va_lnv_b = (const float*)d_in[15];
  const float* va_Wo    = (const float*)d_in[16];
  const float* va_bo    = (const float*)d_in[17];
  const float* va_ln_g  = (const float*)d_in[18];
  const float* va_ln_b  = (const float*)d_in[19];
  const float* va_fi_W1 = (const float*)d_in[20];
  const float* va_fi_b1 = (const float*)d_in[21];
  const float* va_fi_W2 = (const float*)d_in[22];
  const float* va_fi_b2 = (const float*)d_in[23];
  const float* gat_W    = (const float*)d_in[24];
  const float* gat_asrc = (const float*)d_in[25];
  const float* gat_adst = (const float*)d_in[26];
  const float* gat_bias = (const float*)d_in[27];
  const float* imp_W    = (const float*)d_in[28];
  const float* imp_b    = (const float*)d_in[29];
  const float* ga_ln_g  = (const float*)d_in[30];
  const float* ga_ln_b  = (const float*)d_in[31];
  const float* fin_ln_g = (const float*)d_in[32];
  const float* fin_ln_b = (const float*)d_in[33];
  const float* pred_W1  = (const float*)d_in[34];
  const float* pred_b1  = (const float*)d_in[35];
  const float* pred_W2  = (const float*)d_in[36];
  const float* pred_b2  = (const float*)d_in[37];

  float* base   = (float*)d_ws;
  float* emb    = base;
  __hip_bfloat16* obuf = (__hip_bfloat16*)(base + 24576000);   // [NF,256] bf16
  float* smalls = base + 36864000;
  float* wbuf   = smalls;                                      // [NF]
  float* nodeb  = smalls + 192000;
  __hip_bfloat16* xh = (__hip_bfloat16*)(smalls + 1728000);
  __hip_bfloat16* xl = (__hip_bfloat16*)(smalls + 2496000);
  int*   topi   = (int*)(smalls + 3264000);
  int*   boti   = (int*)(smalls + 3456000);
  float* wtb    = smalls + 3648000;
  float* simb   = base;
  // post-topk overlays (dead sim region):
  float* gout   = base + 0;                   // [N,768]
  float* to     = base + 4608000;             // [N,256]
  float* bo     = base + 6144000;             // [N,256]
  float* esb    = base + 7680000;
  float* edb    = base + 7776000;
  unsigned* mu  = (unsigned*)(base + 7872000);
  float* sb     = base + 7968000;
  float* pb     = base + 8064000;             // [2EH]
  float* outv   = base + 11232000;
  int* csr_off  = (int*)(base + 12768000);
  int* csr_cur  = (int*)(base + 12782000);
  int* csr_deg  = (int*)(base + 12794000);
  int* csr_eidx = (int*)(base + 12806000);
  int* csr_tidx = (int*)(base + 13202000);

  // packed weights (inside wtb)
  __hip_bfloat16* wbf    = (__hip_bfloat16*)wtb;
  __hip_bfloat16* predtb = (__hip_bfloat16*)(wtb + 393216);
  float* qkvb   = wtb + 458752;
  float* b3     = wtb + 460288;
  __hip_bfloat16* gwh = (__hip_bfloat16*)(wtb + 461056);

  // --- weight prep
  transpose12_kernel<<<dim3(256, 12), 256, 0, stream>>>(
      va_Wq, va_Wk, va_Wv, va_Wq + 65536, va_Wk + 65536, va_Wv + 65536,
      va_Wo, va_Wo + 65536, va_fi_W1 + (L_-1) * 65536,
      gat_W, gat_W + 65536, gat_W + 131072, wbf);
  transpose_pred_kernel<<<512, 256, 0, stream>>>(pred_W1, predtb);
  biascat_kernel<<<dim3(3, 2), 256, 0, stream>>>(va_bq, va_bk, va_bv, qkvb);
  gatbias_kernel<<<3, 256, 0, stream>>>(gat_bias, b3);
  gruw_cvt_kernel<<<3072, 256, 0, stream>>>(gru_Wih, gwh);

  // --- TimeMixing GRU
  gru_mfma_kernel<<<dim3(2, 94, 16), 256, 0, stream>>>(x, gwh, gru_bih, gru_bhh, emb);

  // --- Variable attention layers: 2 dispatches per layer (2 nodes per block)
  for (int l = 0; l < L_; l++) {
    const __hip_bfloat16* qkvtb = wbf + (size_t)l * 3 * 65536;
    const __hip_bfloat16* wotb  = wbf + (size_t)(6 + l) * 65536;
    qkv_attn2_kernel<<<N_ / 2, 256, 0, stream>>>(emb, qkvtb, qkvb + l * 768, obuf,
                                                 va_lnq_g + l * 256, va_lnq_b + l * 256,
                                                 va_lnk_g + l * 256, va_lnk_b + l * 256,
                                                 va_lnv_g + l * 256, va_lnv_b + l * 256);
    wo_resid_ln_kernel<<<(NF_ + 63) / 64, 256, 0, stream>>>(obuf, wotb, va_bo + l * 256,
                                                            emb, va_ln_g + l * 256,
                                                            va_ln_b + l * 256, NF_);
  }

  // --- feature importance (single dispatch; +b2 dropped: softmax-invariant)
  zero_f_kernel<<<(NF_ + 255) / 256, 256, 0, stream>>>(wbuf, NF_);
  gemm_dot2<<<dim3(2, (NF_ + 127) / 128), 256, 0, stream>>>(emb, wbf + 8 * 65536,
                                                            va_fi_b1 + (L_-1) * 256,
                                                            va_fi_W2 + (L_-1) * 256,
                                                            wbuf, NF_, 256, 256);
  node_prep_kernel<<<N_, 256, 0, stream>>>(wbuf, emb, nodeb, xh, xl);

  // --- cosine similarity + top/bottom-k
  sim_split_kernel<<<dim3(47, 47), 256, 0, stream>>>(xh, xl, simb);
  topk_kernel<<<N_, 256, 0, stream>>>(simb, topi, boti);

  // --- merged self/top/bot projection GEMM -> gout [N,768]
  gemm_fA_bB<0><<<dim3(6, 47), 256, 0, stream>>>(nodeb, wbf + 9 * 65536, b3, gout, N_, 256, 768);

  // --- GAT (both graphs per dispatch)
  const int G_NH2 = (2 * N_ * H_ + 255) / 256;
  const int G_ND2 = (2 * N_ * D_ + 255) / 256;
  const int G_EH2 = (2 * E_ * H_ + 255) / 256;
  const int G_E2  = (2 * E_ + 255) / 256;
  const int G_SEG = (2 * E_ + 63) / 64;
  gat_esed2_kernel<<<G_NH2, 256, 0, stream>>>(gout, gat_asrc, gat_adst, esb, edb);
  gat_init2_kernel<<<G_ND2, 256, 0, stream>>>(mu, sb, to);
  gat_edge_max2_kernel<<<G_EH2, 256, 0, stream>>>(topi, boti, esb, edb, mu);
  gat_edge_sum2_kernel<<<G_EH2, 256, 0, stream>>>(topi, boti, esb, edb, mu, sb, pb);
  csr_zero2_kernel<<<(2 * N_ + 255) / 256, 256, 0, stream>>>(csr_deg);
  csr_count2_kernel<<<G_E2, 256, 0, stream>>>(topi, boti, csr_deg);
  csr_scan2_kernel<<<1, 256, 0, stream>>>(csr_deg, csr_off, csr_cur);
  csr_scatter2_kernel<<<G_E2, 256, 0, stream>>>(topi, boti, csr_cur, csr_eidx, csr_tidx);
  gat_seg2_kernel<<<G_SEG, 256, 0, stream>>>(csr_off + 2 * N_, csr_eidx, csr_tidx, pb, sb,
                                             gout, to);

  // --- gating fuse + double LN (GAT biases folded in)
  fuse_kernel<<<N_, 256, 0, stream>>>(gout, to, bo, gat_bias, imp_W, imp_b, nodeb,
                                      ga_ln_g, ga_ln_b, fin_ln_g, fin_ln_b, outv, 768);

  // --- predictor (fused gelu-dot; d_out seeded with pred_b2)
  init_scalar_kernel<<<(N_ + 255) / 256, 256, 0, stream>>>((float*)d_out, pred_b2, N_);
  gemm_dot2<<<dim3(4, 47), 256, 0, stream>>>(outv, predtb, pred_b1, pred_W2,
                                             (float*)d_out, N_, 256, 512);
}